// Round 2
// baseline (3103.393 us; speedup 1.0000x reference)
//
#include <hip/hip_runtime.h>
#include <hip/hip_bf16.h>
#include <math.h>

typedef __hip_bfloat16 bf16;

static __device__ __forceinline__ float b2f(bf16 x){ return __bfloat162float(x); }
static __device__ __forceinline__ float ldx(const float* p, size_t i){ return p[i]; }
static __device__ __forceinline__ float ldx(const bf16* p, size_t i){ return __bfloat162float(p[i]); }

// ---------------- workspace layout (bytes) ----------------
// Conv phase:   c1o[0,41M) c2o[41,58M) c3o[58,69M) se[69,70M)
// Transformer:  overlays [0,35M) -- c1o dead by then. Peak ~70 MiB.
constexpr size_t MiB = 1ull << 20;
constexpr size_t OFF_C1   = 0;         // bf16 [1600,32,20,20] 40.96 MB
constexpr size_t OFF_C2   = 41*MiB;    // bf16 [1600,64,9,9]   16.6 MB
constexpr size_t OFF_C3   = 58*MiB;    // bf16 [1600,3136]     10.0 MB
constexpr size_t OFF_SE   = 69*MiB;    // f32  [1600,128]      0.82 MB
constexpr size_t OFF_H    = 0;         // f32  [4800,128]
constexpr size_t OFF_XA   = 3*MiB;     // f32  [4800,128]
constexpr size_t OFF_NORM = 6*MiB;     // f32  [4800,128]
constexpr size_t OFF_QKV  = 9*MiB;     // f32  [4800,384]
constexpr size_t OFF_Y    = 17*MiB;    // f32  [4800,128]
constexpr size_t OFF_H1   = 20*MiB;    // f32  [4800,128]
constexpr size_t OFF_MLPH = 23*MiB;    // f32  [4800,512]
constexpr size_t OFF_ADH  = 33*MiB;    // f32  [4800,64]

// ---------------- conv1: f32 [1600,4,84,84] -> relu -> bf16 [1600,32,20,20] ----------------
__global__ __launch_bounds__(256) void conv1_kernel(
    const float* __restrict__ x, const float* __restrict__ w,
    const float* __restrict__ bias, bf16* __restrict__ out)
{
  int idx = blockIdx.x * 256 + threadIdx.x;      // 1600*32*20*5
  int oxg = idx % 5; int r = idx / 5;
  int oy  = r % 20;  r /= 20;
  int oc  = r % 32;  int b = r / 32;
  const float* xb = x + (size_t)b * (4*84*84);
  const float* wc = w + oc * 256;
  float a0=0.f,a1=0.f,a2=0.f,a3=0.f;
  int ox0 = oxg * 4;
  for (int c = 0; c < 4; ++c){
    #pragma unroll
    for (int ky = 0; ky < 8; ++ky){
      int iy = 4*oy + ky;
      const float4* rp4 = (const float4*)(xb + (c*84 + iy)*84 + 4*ox0);
      float in[20];
      #pragma unroll
      for (int i = 0; i < 5; ++i){
        float4 f = rp4[i];
        in[4*i]=f.x; in[4*i+1]=f.y; in[4*i+2]=f.z; in[4*i+3]=f.w;
      }
      const float4* wp4 = (const float4*)(wc + c*64 + ky*8);
      float wv[8];
      { float4 f = wp4[0]; wv[0]=f.x; wv[1]=f.y; wv[2]=f.z; wv[3]=f.w; }
      { float4 f = wp4[1]; wv[4]=f.x; wv[5]=f.y; wv[6]=f.z; wv[7]=f.w; }
      #pragma unroll
      for (int kx = 0; kx < 8; ++kx){
        a0 += in[kx]      * wv[kx];
        a1 += in[4 + kx]  * wv[kx];
        a2 += in[8 + kx]  * wv[kx];
        a3 += in[12 + kx] * wv[kx];
      }
    }
  }
  float bb = bias[oc];
  size_t o = (((size_t)(b*32 + oc)*20 + oy)*20 + ox0);
  out[o+0] = __float2bfloat16(fmaxf(a0 + bb, 0.f));
  out[o+1] = __float2bfloat16(fmaxf(a1 + bb, 0.f));
  out[o+2] = __float2bfloat16(fmaxf(a2 + bb, 0.f));
  out[o+3] = __float2bfloat16(fmaxf(a3 + bb, 0.f));
}

// ---------------- conv2: bf16 [1600,32,20,20] -> relu -> bf16 [1600,64,9,9] ----------------
__global__ __launch_bounds__(256) void conv2_kernel(
    const bf16* __restrict__ x, const float* __restrict__ w,
    const float* __restrict__ bias, bf16* __restrict__ out)
{
  int idx = blockIdx.x*256 + threadIdx.x;        // 1600*64*9
  int oy = idx % 9; int r = idx / 9;
  int oc = r & 63; int b = r >> 6;
  const bf16* xb = x + (size_t)b * (32*400);
  const float* wb = w + oc * 512;
  float acc[9] = {0,0,0,0,0,0,0,0,0};
  for (int c = 0; c < 32; ++c){
    #pragma unroll
    for (int ky = 0; ky < 4; ++ky){
      int iy = 2*oy + ky;
      const bf16* rowp = xb + (c*20 + iy)*20;
      float in[20];
      #pragma unroll
      for (int i=0;i<20;++i) in[i] = b2f(rowp[i]);
      const float4* wp4 = (const float4*)(wb + c*16 + ky*4);
      float4 wf = wp4[0];
      float wv[4] = {wf.x, wf.y, wf.z, wf.w};
      #pragma unroll
      for (int kx=0;kx<4;++kx)
        #pragma unroll
        for (int ox=0;ox<9;++ox) acc[ox] += in[2*ox+kx]*wv[kx];
    }
  }
  float bb = bias[oc];
  size_t o = ((size_t)(b*64+oc)*9 + oy)*9;
  #pragma unroll
  for (int ox=0;ox<9;++ox) out[o+ox] = __float2bfloat16(fmaxf(acc[ox]+bb, 0.f));
}

// ---------------- conv3: bf16 [1600,64,9,9] -> relu -> bf16 [1600,3136] ----------------
__global__ __launch_bounds__(256) void conv3_kernel(
    const bf16* __restrict__ x, const float* __restrict__ w,
    const float* __restrict__ bias, bf16* __restrict__ out)
{
  int idx = blockIdx.x*256 + threadIdx.x;        // 1600*64*7
  int oy = idx % 7; int r = idx / 7;
  int oc = r & 63; int b = r >> 6;
  const bf16* xb = x + (size_t)b * (64*81);
  const float* wb = w + oc * 576;
  float acc[7] = {0,0,0,0,0,0,0};
  for (int c = 0; c < 64; ++c){
    #pragma unroll
    for (int ky = 0; ky < 3; ++ky){
      const bf16* rowp = xb + c*81 + (oy+ky)*9;
      float in[9];
      #pragma unroll
      for (int i=0;i<9;++i) in[i] = b2f(rowp[i]);
      const float* wp = wb + c*9 + ky*3;
      float w0 = wp[0], w1 = wp[1], w2 = wp[2];
      #pragma unroll
      for (int ox=0;ox<7;++ox) acc[ox] += in[ox]*w0 + in[ox+1]*w1 + in[ox+2]*w2;
    }
  }
  float bb = bias[oc];
  size_t o = (size_t)b*3136 + (oc*7 + oy)*7;
  #pragma unroll
  for (int ox=0;ox<7;++ox) out[o+ox] = __float2bfloat16(fmaxf(acc[ox]+bb, 0.f));
}

// ---------------- token build + pos embedding -> h f32 [4800,128] ----------------
__global__ __launch_bounds__(256) void token_kernel(
    const float* __restrict__ rtgs, const int* __restrict__ actions, const int* __restrict__ timesteps,
    const float* __restrict__ ret_w, const float* __restrict__ ret_b, const float* __restrict__ act_tab,
    const float* __restrict__ pos_emb, const float* __restrict__ gpe,
    const float* __restrict__ se, float* __restrict__ h)
{
  int idx = blockIdx.x*256 + threadIdx.x;   // 4800*128
  int c = idx & 127; int row = idx >> 7;
  int s = row % 150; int b = row / 150;
  int t = s / 3; int r = s - 3*t;
  float tok;
  if (r == 0)      tok = tanhf(rtgs[b*50+t] * ret_w[c] + ret_b[c]);
  else if (r == 1) tok = se[(b*50+t)*128 + c];   // already tanh'ed
  else             tok = tanhf(act_tab[actions[b*50+t]*128 + c]);
  float pe = gpe[(size_t)timesteps[b]*128 + c] + pos_emb[s*128 + c];
  h[idx] = tok + pe;
}

// ---------------- LayerNorm over C=128; one wave per row; optional second output ----------------
__global__ __launch_bounds__(256) void ln_kernel(
    const float* __restrict__ x,
    const float* __restrict__ g1, const float* __restrict__ be1, float* __restrict__ o1,
    const float* __restrict__ g2, const float* __restrict__ be2, float* o2)
{
  int lane = threadIdx.x & 63;
  int row = blockIdx.x*4 + (threadIdx.x >> 6);   // grid 1200 -> 4800 rows
  const float2 xv = *(const float2*)(x + (size_t)row*128 + lane*2);
  float s = xv.x + xv.y, sq = xv.x*xv.x + xv.y*xv.y;
  #pragma unroll
  for (int off = 32; off; off >>= 1){ s += __shfl_xor(s, off); sq += __shfl_xor(sq, off); }
  float mean = s * 0.0078125f;
  float var  = sq * 0.0078125f - mean*mean;
  float rstd = rsqrtf(var + 1e-5f);
  float n0 = (xv.x - mean)*rstd, n1 = (xv.y - mean)*rstd;
  int c0 = lane*2;
  float2 r1; r1.x = n0*g1[c0] + be1[c0]; r1.y = n1*g1[c0+1] + be1[c0+1];
  *(float2*)(o1 + (size_t)row*128 + c0) = r1;
  if (o2){
    float2 r2; r2.x = n0*g2[c0] + be2[c0]; r2.y = n1*g2[c0+1] + be2[c0+1];
    *(float2*)(o2 + (size_t)row*128 + c0) = r2;
  }
}

// ---------------- generic tiled GEMM: out = ACT(X @ W^T + bias) + add_scale*add ----------------
// X [M,K] (f32 or bf16), W f32 [N,K], M%64==0, N%64==0 (or N==64k), K%32==0
// ACT: 0=none, 1=tanh, 2=gelu(exact), 3=relu
template<int ACT, typename XT>
__global__ __launch_bounds__(256) void gemm_kernel(
    const XT* __restrict__ X, const float* __restrict__ W,
    const float* __restrict__ bias, const float* add, float add_scale,
    float* out, int M, int N, int K)
{
  __shared__ float Xs[64][33];
  __shared__ float Ws[64][33];
  int nb = N >> 6;
  int bn = (blockIdx.x % nb) << 6;
  int bm = (blockIdx.x / nb) << 6;
  int t = threadIdx.x;
  int tx = t & 15, ty = t >> 4;
  float acc[4][4] = {};
  for (int k0 = 0; k0 < K; k0 += 32){
    #pragma unroll
    for (int i = 0; i < 8; ++i){
      int e = t + (i << 8);
      int rr = e >> 5, cc = e & 31;
      Xs[rr][cc] = ldx(X, (size_t)(bm + rr)*K + k0 + cc);
      Ws[rr][cc] = W[(size_t)(bn + rr)*K + k0 + cc];
    }
    __syncthreads();
    #pragma unroll
    for (int kk = 0; kk < 32; ++kk){
      float xv[4], wv[4];
      #pragma unroll
      for (int r2 = 0; r2 < 4; ++r2){ xv[r2] = Xs[ty*4+r2][kk]; wv[r2] = Ws[tx*4+r2][kk]; }
      #pragma unroll
      for (int i = 0; i < 4; ++i)
        #pragma unroll
        for (int j = 0; j < 4; ++j) acc[i][j] += xv[i]*wv[j];
    }
    __syncthreads();
  }
  #pragma unroll
  for (int i = 0; i < 4; ++i){
    int m = bm + ty*4 + i;
    #pragma unroll
    for (int j = 0; j < 4; ++j){
      int n = bn + tx*4 + j;
      float v = acc[i][j] + bias[n];
      if (ACT == 1) v = tanhf(v);
      else if (ACT == 2) v = 0.5f*v*(1.0f + erff(v*0.70710678118f));
      else if (ACT == 3) v = fmaxf(v, 0.f);
      if (add) v += add_scale * add[(size_t)m*N + n];
      out[(size_t)m*N + n] = v;
    }
  }
}

// ---------------- attention: qkv f32 [4800, 384] (k|q|v), causal, online softmax ----------------
__global__ __launch_bounds__(256) void attn_kernel(const float* __restrict__ qkv, float* __restrict__ y)
{
  int bh = blockIdx.x;          // 32*8
  int hh = bh & 7; int b = bh >> 3;
  __shared__ float ks[150*16];
  __shared__ float vs[150*16];
  int t = threadIdx.x;
  for (int i = t; i < 2400; i += 256){
    int s = i >> 4; int d = i & 15;
    const float* base = qkv + (size_t)(b*150 + s)*384;
    ks[i] = base[hh*16 + d];
    vs[i] = base[256 + hh*16 + d];
  }
  __syncthreads();
  if (t < 150){
    const float* qr = qkv + (size_t)(b*150 + t)*384 + 128 + hh*16;
    float q[16];
    #pragma unroll
    for (int d = 0; d < 16; ++d) q[d] = qr[d] * 0.25f;   // scale = 1/sqrt(16)
    float m = -1e30f, l = 0.f, acc[16] = {};
    for (int j = 0; j <= t; ++j){
      const float* kr = ks + j*16;
      float s = 0.f;
      #pragma unroll
      for (int d = 0; d < 16; ++d) s += q[d]*kr[d];
      float mn = fmaxf(m, s);
      float corr = __expf(m - mn);
      float p = __expf(s - mn);
      l = l*corr + p;
      const float* vr = vs + j*16;
      #pragma unroll
      for (int d = 0; d < 16; ++d) acc[d] = acc[d]*corr + p*vr[d];
      m = mn;
    }
    float inv = 1.f / l;
    float* yr = y + (size_t)(b*150 + t)*128 + hh*16;
    #pragma unroll
    for (int d = 0; d < 16; ++d) yr[d] = acc[d]*inv;
  }
}

// ---------------- fused final LN + head on state tokens only -> f32 [1600,18] ----------------
__global__ __launch_bounds__(64) void head_kernel(
    const float* __restrict__ h, const float* __restrict__ g, const float* __restrict__ be,
    const float* __restrict__ hw, float* __restrict__ out)
{
  int bt = blockIdx.x;          // 1600 = b*50+t
  int lane = threadIdx.x;
  int b = bt / 50, t = bt % 50;
  const float* row = h + ((size_t)b*150 + 3*t + 1)*128;
  float2 xv = *(const float2*)(row + lane*2);
  float s = xv.x + xv.y, sq = xv.x*xv.x + xv.y*xv.y;
  #pragma unroll
  for (int off = 32; off; off >>= 1){ s += __shfl_xor(s, off); sq += __shfl_xor(sq, off); }
  float mean = s * 0.0078125f;
  float var  = sq * 0.0078125f - mean*mean;
  float rstd = rsqrtf(var + 1e-5f);
  int c0 = lane*2;
  __shared__ float sh[128];
  sh[c0]   = (xv.x-mean)*rstd*g[c0]   + be[c0];
  sh[c0+1] = (xv.y-mean)*rstd*g[c0+1] + be[c0+1];
  __syncthreads();
  if (lane < 18){
    const float* wr = hw + lane*128;
    float acc = 0.f;
    #pragma unroll
    for (int c = 0; c < 128; c += 4){
      float4 wf = *(const float4*)(wr + c);
      acc += sh[c]*wf.x + sh[c+1]*wf.y + sh[c+2]*wf.z + sh[c+3]*wf.w;
    }
    out[bt*18 + lane] = acc;
  }
}

// ---------------- launch ----------------
extern "C" void kernel_launch(void* const* d_in, const int* in_sizes, int n_in,
                              void* d_out, int out_size, void* d_ws, size_t ws_size,
                              hipStream_t stream)
{
  const float* states    = (const float*)d_in[0];
  const float* rtgs      = (const float*)d_in[1];
  const int*   actions   = (const int*)d_in[2];
  const int*   timesteps = (const int*)d_in[3];
  // d_in[4] targets unused
  const float* pos_emb   = (const float*)d_in[5];
  const float* gpe       = (const float*)d_in[6];
  const float* c1_w = (const float*)d_in[7];  const float* c1_b = (const float*)d_in[8];
  const float* c2_w = (const float*)d_in[9];  const float* c2_b = (const float*)d_in[10];
  const float* c3_w = (const float*)d_in[11]; const float* c3_b = (const float*)d_in[12];
  const float* enc_w = (const float*)d_in[13]; const float* enc_b = (const float*)d_in[14];
  const float* ret_w = (const float*)d_in[15]; const float* ret_b = (const float*)d_in[16];
  const float* act_tab = (const float*)d_in[17];
  const float* ln_w = (const float*)d_in[18]; const float* ln_b = (const float*)d_in[19];
  const float* attn_w = (const float*)d_in[20]; const float* attn_b = (const float*)d_in[21];
  const float* mlp_w1 = (const float*)d_in[22]; const float* mlp_b1 = (const float*)d_in[23];
  const float* mlp_w2 = (const float*)d_in[24]; const float* mlp_b2 = (const float*)d_in[25];
  const float* ad_dw = (const float*)d_in[26]; const float* ad_db = (const float*)d_in[27];
  const float* ad_uw = (const float*)d_in[28]; const float* ad_ub = (const float*)d_in[29];
  const float* lnf_w = (const float*)d_in[30]; const float* lnf_b = (const float*)d_in[31];
  const float* head_w = (const float*)d_in[32];
  float* out = (float*)d_out;

  char* ws = (char*)d_ws;
  bf16* c1o  = (bf16*)(ws + OFF_C1);
  bf16* c2o  = (bf16*)(ws + OFF_C2);
  bf16* c3o  = (bf16*)(ws + OFF_C3);
  float* se   = (float*)(ws + OFF_SE);
  float* h    = (float*)(ws + OFF_H);
  float* xa   = (float*)(ws + OFF_XA);
  float* nrm  = (float*)(ws + OFF_NORM);
  float* qkv  = (float*)(ws + OFF_QKV);
  float* y    = (float*)(ws + OFF_Y);
  float* h1   = (float*)(ws + OFF_H1);
  float* mlph = (float*)(ws + OFF_MLPH);
  float* adh  = (float*)(ws + OFF_ADH);

  conv1_kernel<<<20000, 256, 0, stream>>>(states, c1_w, c1_b, c1o);
  conv2_kernel<<<3600, 256, 0, stream>>>(c1o, c2_w, c2_b, c2o);
  conv3_kernel<<<2800, 256, 0, stream>>>(c2o, c3_w, c3_b, c3o);
  // state_e = tanh(c3o @ enc_w^T + enc_b): M=1600, N=128, K=3136
  gemm_kernel<1, bf16><<<25*2, 256, 0, stream>>>(c3o, enc_w, enc_b, nullptr, 0.f, se, 1600, 128, 3136);
  token_kernel<<<2400, 256, 0, stream>>>(rtgs, actions, timesteps, ret_w, ret_b, act_tab,
                                         pos_emb, gpe, se, h);

  for (int l = 0; l < 6; ++l){
    const float* g1 = ln_w + (l*3+0)*128; const float* be1 = ln_b + (l*3+0)*128;
    const float* g2 = ln_w + (l*3+1)*128; const float* be2 = ln_b + (l*3+1)*128;
    const float* g3 = ln_w + (l*3+2)*128; const float* be3 = ln_b + (l*3+2)*128;
    // ln1 -> xa, ln3 -> nrm (shared stats)
    ln_kernel<<<1200, 256, 0, stream>>>(h, g1, be1, xa, g3, be3, nrm);
    // k|q|v = xa @ attn_w[l,0..2]^T + b   (N=384)
    gemm_kernel<0, float><<<75*6, 256, 0, stream>>>(xa, attn_w + (size_t)l*4*16384, attn_b + l*4*128,
                                                    nullptr, 0.f, qkv, 4800, 384, 128);
    attn_kernel<<<256, 256, 0, stream>>>(qkv, y);
    // h1 = h + y @ attn_w[l,3]^T + b
    gemm_kernel<0, float><<<75*2, 256, 0, stream>>>(y, attn_w + ((size_t)l*4+3)*16384, attn_b + (l*4+3)*128,
                                                    h, 1.0f, h1, 4800, 128, 128);
    // ln2 -> xa
    ln_kernel<<<1200, 256, 0, stream>>>(h1, g2, be2, xa, nullptr, nullptr, nullptr);
    // mlp hidden = gelu(xa @ w1^T + b1)
    gemm_kernel<2, float><<<75*8, 256, 0, stream>>>(xa, mlp_w1 + (size_t)l*65536, mlp_b1 + l*512,
                                                    nullptr, 0.f, mlph, 4800, 512, 128);
    // adapter hidden = relu(nrm @ dw^T + db)
    gemm_kernel<3, float><<<75*1, 256, 0, stream>>>(nrm, ad_dw + (size_t)l*8192, ad_db + l*64,
                                                    nullptr, 0.f, adh, 4800, 64, 128);
    // h = 2*h1 + mlph @ w2^T + b2
    gemm_kernel<0, float><<<75*2, 256, 0, stream>>>(mlph, mlp_w2 + (size_t)l*65536, mlp_b2 + l*128,
                                                    h1, 2.0f, h, 4800, 128, 512);
    // h += adh @ uw^T + ub
    gemm_kernel<0, float><<<75*2, 256, 0, stream>>>(adh, ad_uw + (size_t)l*8192, ad_ub + l*128,
                                                    h, 1.0f, h, 4800, 128, 64);
  }
  head_kernel<<<1600, 64, 0, stream>>>(h, lnf_w, lnf_b, head_w, out);
}

// Round 3
// 2141.762 us; speedup vs baseline: 1.4490x; 1.4490x over previous
//
#include <hip/hip_runtime.h>
#include <hip/hip_bf16.h>
#include <math.h>

typedef __hip_bfloat16 bf16;

static __device__ __forceinline__ float b2f(bf16 x){ return __bfloat162float(x); }
static __device__ __forceinline__ float ldx(const float* p, size_t i){ return p[i]; }
static __device__ __forceinline__ float ldx(const bf16* p, size_t i){ return __bfloat162float(p[i]); }

// unpack 2 bf16 packed in a uint32 (little-endian: elem0 = low 16 bits)
static __device__ __forceinline__ float2 upk2(unsigned int u){
  union { unsigned int i; float f; } a, b;
  a.i = u << 16;
  b.i = u & 0xffff0000u;
  float2 r; r.x = a.f; r.y = b.f; return r;
}

// ---------------- workspace layout (bytes) ----------------
constexpr size_t MiB = 1ull << 20;
constexpr size_t OFF_C1   = 0;         // bf16 [1600,32,20,20] 40.96 MB
constexpr size_t OFF_C2   = 41*MiB;    // bf16 [1600,64,9,9]   16.6 MB
constexpr size_t OFF_C3   = 58*MiB;    // bf16 [1600,3136]     10.0 MB
constexpr size_t OFF_SE   = 69*MiB;    // f32  [1600,128]      0.82 MB
constexpr size_t OFF_H    = 0;         // f32  [4800,128]
constexpr size_t OFF_XA   = 3*MiB;     // f32  [4800,128]
constexpr size_t OFF_NORM = 6*MiB;     // f32  [4800,128]
constexpr size_t OFF_QKV  = 9*MiB;     // f32  [4800,384]
constexpr size_t OFF_Y    = 17*MiB;    // f32  [4800,128]
constexpr size_t OFF_H1   = 20*MiB;    // f32  [4800,128]
constexpr size_t OFF_MLPH = 23*MiB;    // f32  [4800,512]
constexpr size_t OFF_ADH  = 33*MiB;    // f32  [4800,64]

// ---------------- conv1: f32 [1600,4,84,84] -> relu -> bf16 [1600,32,20,20] ----------------
// block = (image, 4-row output strip). LDS-stage input strip once, reuse across 32 oc.
__global__ __launch_bounds__(256) void conv1_kernel(
    const float* __restrict__ x, const float* __restrict__ w,
    const float* __restrict__ bias, bf16* __restrict__ out)
{
  __shared__ float xs[4][20][85];
  int b = blockIdx.x / 5, g = blockIdx.x % 5;
  int t = threadIdx.x;
  const float* xb = x + (size_t)b*(4*84*84) + (size_t)(16*g)*84;
  for (int e = t; e < 1680; e += 256){
    int c = e / 420, rem = e % 420;
    int row = rem / 21, c4 = (rem % 21)*4;
    float4 f = *(const float4*)(xb + (c*84 + row)*84 + c4);
    xs[c][row][c4] = f.x; xs[c][row][c4+1] = f.y; xs[c][row][c4+2] = f.z; xs[c][row][c4+3] = f.w;
  }
  __syncthreads();
  int oc = t >> 3, oy4 = (t >> 1) & 3, oxh = t & 1;
  float acc[10] = {};
  const float* wc = w + oc*256;
  for (int c = 0; c < 4; ++c){
    for (int ky = 0; ky < 8; ++ky){
      float seg[44];
      const float* rowp = &xs[c][4*oy4 + ky][40*oxh];
      #pragma unroll
      for (int i = 0; i < 44; ++i) seg[i] = rowp[i];
      const float4* wp4 = (const float4*)(wc + c*64 + ky*8);
      float4 wa = wp4[0], wb2 = wp4[1];
      float wv[8] = {wa.x,wa.y,wa.z,wa.w, wb2.x,wb2.y,wb2.z,wb2.w};
      #pragma unroll
      for (int kx = 0; kx < 8; ++kx)
        #pragma unroll
        for (int ox = 0; ox < 10; ++ox)
          acc[ox] += seg[4*ox+kx] * wv[kx];
    }
  }
  float bb = bias[oc];
  int oy = 4*g + oy4;
  size_t o = (((size_t)(b*32+oc)*20 + oy)*20 + 10*oxh);
  #pragma unroll
  for (int ox = 0; ox < 10; ++ox) out[o+ox] = __float2bfloat16(fmaxf(acc[ox]+bb, 0.f));
}

// ---------------- conv2: bf16 [1600,32,20,20] -> relu -> bf16 [1600,64,9,9] ----------------
// block = (image, 3-oy strip). LDS-stage 8 input rows x 32 ch; lanes share oc-major
// layout so each (c,ky) LDS row read is a 64-lane broadcast (conflict-free).
__global__ __launch_bounds__(192) void conv2_kernel(
    const bf16* __restrict__ x, const float* __restrict__ w,
    const float* __restrict__ bias, bf16* __restrict__ out)
{
  __shared__ float xs[32][8][21];
  int b = blockIdx.x / 3, g = blockIdx.x % 3;
  int t = threadIdx.x;
  const bf16* xb = x + (size_t)b*(32*400) + 6*g*20;
  for (int e = t; e < 2560; e += 192){
    int c = e / 80, rem = e % 80;
    int r = rem / 10, cp = rem % 10;
    unsigned int u = *(const unsigned int*)(xb + (c*20 + r)*20 + 2*cp);
    float2 f = upk2(u);
    xs[c][r][2*cp] = f.x; xs[c][r][2*cp+1] = f.y;
  }
  __syncthreads();
  int oc = t % 64, oyl = t / 64;   // 64 oc x 3 oy
  float acc[9] = {};
  const float* wb = w + oc*512;
  for (int c = 0; c < 32; ++c){
    #pragma unroll
    for (int ky = 0; ky < 4; ++ky){
      const float* rowp = xs[c][2*oyl + ky];
      float seg[20];
      #pragma unroll
      for (int i = 0; i < 20; ++i) seg[i] = rowp[i];
      float4 wf = *(const float4*)(wb + c*16 + ky*4);
      float wv[4] = {wf.x, wf.y, wf.z, wf.w};
      #pragma unroll
      for (int kx = 0; kx < 4; ++kx)
        #pragma unroll
        for (int ox = 0; ox < 9; ++ox) acc[ox] += seg[2*ox+kx]*wv[kx];
    }
  }
  int oy = 3*g + oyl;
  float bb = bias[oc];
  size_t o = ((size_t)(b*64+oc)*9 + oy)*9;
  #pragma unroll
  for (int ox = 0; ox < 9; ++ox) out[o+ox] = __float2bfloat16(fmaxf(acc[ox]+bb, 0.f));
}

// ---------------- conv3: bf16 [1600,64,9,9] -> relu -> bf16 [1600,3136] ----------------
// block = image. Full input (20.7 KB) staged; thread = (oc, oy) + optional (oc, oy+4).
__global__ __launch_bounds__(256) void conv3_kernel(
    const bf16* __restrict__ x, const float* __restrict__ w,
    const float* __restrict__ bias, bf16* __restrict__ out)
{
  __shared__ float xsf[5184];   // [64][81]
  int b = blockIdx.x;
  int t = threadIdx.x;
  const bf16* xb = x + (size_t)b*5184;
  for (int e = t; e < 2592; e += 256){
    unsigned int u = *(const unsigned int*)(xb + 2*e);
    float2 f = upk2(u);
    xsf[2*e] = f.x; xsf[2*e+1] = f.y;
  }
  __syncthreads();
  int oc = t & 63;
  int oy1 = t >> 6;             // 0..3
  bool two = (t < 192);         // second item: oy1+4 in 4..6
  float a1[7] = {}, a2[7] = {};
  const float* wb3 = w + oc*576;
  for (int c = 0; c < 64; ++c){
    #pragma unroll
    for (int ky = 0; ky < 3; ++ky){
      const float* wp = wb3 + c*9 + ky*3;
      float w0 = wp[0], w1 = wp[1], w2 = wp[2];
      const float* r1 = xsf + c*81 + (oy1+ky)*9;
      #pragma unroll
      for (int ox = 0; ox < 7; ++ox) a1[ox] += r1[ox]*w0 + r1[ox+1]*w1 + r1[ox+2]*w2;
      if (two){
        const float* r2 = xsf + c*81 + (oy1+4+ky)*9;
        #pragma unroll
        for (int ox = 0; ox < 7; ++ox) a2[ox] += r2[ox]*w0 + r2[ox+1]*w1 + r2[ox+2]*w2;
      }
    }
  }
  float bb = bias[oc];
  size_t o1 = (size_t)b*3136 + oc*49 + oy1*7;
  #pragma unroll
  for (int ox = 0; ox < 7; ++ox) out[o1+ox] = __float2bfloat16(fmaxf(a1[ox]+bb, 0.f));
  if (two){
    size_t o2 = (size_t)b*3136 + oc*49 + (oy1+4)*7;
    #pragma unroll
    for (int ox = 0; ox < 7; ++ox) out[o2+ox] = __float2bfloat16(fmaxf(a2[ox]+bb, 0.f));
  }
}

// ---------------- token build + pos embedding -> h f32 [4800,128] ----------------
__global__ __launch_bounds__(256) void token_kernel(
    const float* __restrict__ rtgs, const int* __restrict__ actions, const int* __restrict__ timesteps,
    const float* __restrict__ ret_w, const float* __restrict__ ret_b, const float* __restrict__ act_tab,
    const float* __restrict__ pos_emb, const float* __restrict__ gpe,
    const float* __restrict__ se, float* __restrict__ h)
{
  int idx = blockIdx.x*256 + threadIdx.x;   // 4800*128
  int c = idx & 127; int row = idx >> 7;
  int s = row % 150; int b = row / 150;
  int t = s / 3; int r = s - 3*t;
  float tok;
  if (r == 0)      tok = tanhf(rtgs[b*50+t] * ret_w[c] + ret_b[c]);
  else if (r == 1) tok = se[(b*50+t)*128 + c];   // already tanh'ed
  else             tok = tanhf(act_tab[actions[b*50+t]*128 + c]);
  float pe = gpe[(size_t)timesteps[b]*128 + c] + pos_emb[s*128 + c];
  h[idx] = tok + pe;
}

// ---------------- LayerNorm over C=128; one wave per row; optional second output ----------------
__global__ __launch_bounds__(256) void ln_kernel(
    const float* __restrict__ x,
    const float* __restrict__ g1, const float* __restrict__ be1, float* __restrict__ o1,
    const float* __restrict__ g2, const float* __restrict__ be2, float* o2)
{
  int lane = threadIdx.x & 63;
  int row = blockIdx.x*4 + (threadIdx.x >> 6);   // grid 1200 -> 4800 rows
  const float2 xv = *(const float2*)(x + (size_t)row*128 + lane*2);
  float s = xv.x + xv.y, sq = xv.x*xv.x + xv.y*xv.y;
  #pragma unroll
  for (int off = 32; off; off >>= 1){ s += __shfl_xor(s, off); sq += __shfl_xor(sq, off); }
  float mean = s * 0.0078125f;
  float var  = sq * 0.0078125f - mean*mean;
  float rstd = rsqrtf(var + 1e-5f);
  float n0 = (xv.x - mean)*rstd, n1 = (xv.y - mean)*rstd;
  int c0 = lane*2;
  float2 r1; r1.x = n0*g1[c0] + be1[c0]; r1.y = n1*g1[c0+1] + be1[c0+1];
  *(float2*)(o1 + (size_t)row*128 + c0) = r1;
  if (o2){
    float2 r2; r2.x = n0*g2[c0] + be2[c0]; r2.y = n1*g2[c0+1] + be2[c0+1];
    *(float2*)(o2 + (size_t)row*128 + c0) = r2;
  }
}

// ---------------- generic tiled GEMM: out = ACT(X @ W^T + bias) + add_scale*add ----------------
// X [M,K] (f32 or bf16), W f32 [N,K], M%64==0, N%64==0, K%32==0
// ACT: 0=none, 1=tanh, 2=gelu(exact), 3=relu
template<int ACT, typename XT>
__global__ __launch_bounds__(256) void gemm_kernel(
    const XT* __restrict__ X, const float* __restrict__ W,
    const float* __restrict__ bias, const float* add, float add_scale,
    float* out, int M, int N, int K)
{
  __shared__ float Xs[64][33];
  __shared__ float Ws[64][33];
  int nb = N >> 6;
  int bn = (blockIdx.x % nb) << 6;
  int bm = (blockIdx.x / nb) << 6;
  int t = threadIdx.x;
  int tx = t & 15, ty = t >> 4;
  float acc[4][4] = {};
  for (int k0 = 0; k0 < K; k0 += 32){
    #pragma unroll
    for (int i = 0; i < 8; ++i){
      int e = t + (i << 8);
      int rr = e >> 5, cc = e & 31;
      Xs[rr][cc] = ldx(X, (size_t)(bm + rr)*K + k0 + cc);
      Ws[rr][cc] = W[(size_t)(bn + rr)*K + k0 + cc];
    }
    __syncthreads();
    #pragma unroll
    for (int kk = 0; kk < 32; ++kk){
      float xv[4], wv[4];
      #pragma unroll
      for (int r2 = 0; r2 < 4; ++r2){ xv[r2] = Xs[ty*4+r2][kk]; wv[r2] = Ws[tx*4+r2][kk]; }
      #pragma unroll
      for (int i = 0; i < 4; ++i)
        #pragma unroll
        for (int j = 0; j < 4; ++j) acc[i][j] += xv[i]*wv[j];
    }
    __syncthreads();
  }
  #pragma unroll
  for (int i = 0; i < 4; ++i){
    int m = bm + ty*4 + i;
    #pragma unroll
    for (int j = 0; j < 4; ++j){
      int n = bn + tx*4 + j;
      float v = acc[i][j] + bias[n];
      if (ACT == 1) v = tanhf(v);
      else if (ACT == 2) v = 0.5f*v*(1.0f + erff(v*0.70710678118f));
      else if (ACT == 3) v = fmaxf(v, 0.f);
      if (add) v += add_scale * add[(size_t)m*N + n];
      out[(size_t)m*N + n] = v;
    }
  }
}

// ---------------- attention: qkv f32 [4800, 384] (k|q|v), causal, online softmax ----------------
__global__ __launch_bounds__(256) void attn_kernel(const float* __restrict__ qkv, float* __restrict__ y)
{
  int bh = blockIdx.x;          // 32*8
  int hh = bh & 7; int b = bh >> 3;
  __shared__ float ks[150*16];
  __shared__ float vs[150*16];
  int t = threadIdx.x;
  for (int i = t; i < 2400; i += 256){
    int s = i >> 4; int d = i & 15;
    const float* base = qkv + (size_t)(b*150 + s)*384;
    ks[i] = base[hh*16 + d];
    vs[i] = base[256 + hh*16 + d];
  }
  __syncthreads();
  if (t < 150){
    const float* qr = qkv + (size_t)(b*150 + t)*384 + 128 + hh*16;
    float q[16];
    #pragma unroll
    for (int d = 0; d < 16; ++d) q[d] = qr[d] * 0.25f;   // scale = 1/sqrt(16)
    float m = -1e30f, l = 0.f, acc[16] = {};
    for (int j = 0; j <= t; ++j){
      const float* kr = ks + j*16;
      float s = 0.f;
      #pragma unroll
      for (int d = 0; d < 16; ++d) s += q[d]*kr[d];
      float mn = fmaxf(m, s);
      float corr = __expf(m - mn);
      float p = __expf(s - mn);
      l = l*corr + p;
      const float* vr = vs + j*16;
      #pragma unroll
      for (int d = 0; d < 16; ++d) acc[d] = acc[d]*corr + p*vr[d];
      m = mn;
    }
    float inv = 1.f / l;
    float* yr = y + (size_t)(b*150 + t)*128 + hh*16;
    #pragma unroll
    for (int d = 0; d < 16; ++d) yr[d] = acc[d]*inv;
  }
}

// ---------------- fused final LN + head on state tokens only -> f32 [1600,18] ----------------
__global__ __launch_bounds__(64) void head_kernel(
    const float* __restrict__ h, const float* __restrict__ g, const float* __restrict__ be,
    const float* __restrict__ hw, float* __restrict__ out)
{
  int bt = blockIdx.x;          // 1600 = b*50+t
  int lane = threadIdx.x;
  int b = bt / 50, t = bt % 50;
  const float* row = h + ((size_t)b*150 + 3*t + 1)*128;
  float2 xv = *(const float2*)(row + lane*2);
  float s = xv.x + xv.y, sq = xv.x*xv.x + xv.y*xv.y;
  #pragma unroll
  for (int off = 32; off; off >>= 1){ s += __shfl_xor(s, off); sq += __shfl_xor(sq, off); }
  float mean = s * 0.0078125f;
  float var  = sq * 0.0078125f - mean*mean;
  float rstd = rsqrtf(var + 1e-5f);
  int c0 = lane*2;
  __shared__ float sh[128];
  sh[c0]   = (xv.x-mean)*rstd*g[c0]   + be[c0];
  sh[c0+1] = (xv.y-mean)*rstd*g[c0+1] + be[c0+1];
  __syncthreads();
  if (lane < 18){
    const float* wr = hw + lane*128;
    float acc = 0.f;
    #pragma unroll
    for (int c = 0; c < 128; c += 4){
      float4 wf = *(const float4*)(wr + c);
      acc += sh[c]*wf.x + sh[c+1]*wf.y + sh[c+2]*wf.z + sh[c+3]*wf.w;
    }
    out[bt*18 + lane] = acc;
  }
}

// ---------------- launch ----------------
extern "C" void kernel_launch(void* const* d_in, const int* in_sizes, int n_in,
                              void* d_out, int out_size, void* d_ws, size_t ws_size,
                              hipStream_t stream)
{
  const float* states    = (const float*)d_in[0];
  const float* rtgs      = (const float*)d_in[1];
  const int*   actions   = (const int*)d_in[2];
  const int*   timesteps = (const int*)d_in[3];
  // d_in[4] targets unused
  const float* pos_emb   = (const float*)d_in[5];
  const float* gpe       = (const float*)d_in[6];
  const float* c1_w = (const float*)d_in[7];  const float* c1_b = (const float*)d_in[8];
  const float* c2_w = (const float*)d_in[9];  const float* c2_b = (const float*)d_in[10];
  const float* c3_w = (const float*)d_in[11]; const float* c3_b = (const float*)d_in[12];
  const float* enc_w = (const float*)d_in[13]; const float* enc_b = (const float*)d_in[14];
  const float* ret_w = (const float*)d_in[15]; const float* ret_b = (const float*)d_in[16];
  const float* act_tab = (const float*)d_in[17];
  const float* ln_w = (const float*)d_in[18]; const float* ln_b = (const float*)d_in[19];
  const float* attn_w = (const float*)d_in[20]; const float* attn_b = (const float*)d_in[21];
  const float* mlp_w1 = (const float*)d_in[22]; const float* mlp_b1 = (const float*)d_in[23];
  const float* mlp_w2 = (const float*)d_in[24]; const float* mlp_b2 = (const float*)d_in[25];
  const float* ad_dw = (const float*)d_in[26]; const float* ad_db = (const float*)d_in[27];
  const float* ad_uw = (const float*)d_in[28]; const float* ad_ub = (const float*)d_in[29];
  const float* lnf_w = (const float*)d_in[30]; const float* lnf_b = (const float*)d_in[31];
  const float* head_w = (const float*)d_in[32];
  float* out = (float*)d_out;

  char* ws = (char*)d_ws;
  bf16* c1o  = (bf16*)(ws + OFF_C1);
  bf16* c2o  = (bf16*)(ws + OFF_C2);
  bf16* c3o  = (bf16*)(ws + OFF_C3);
  float* se   = (float*)(ws + OFF_SE);
  float* h    = (float*)(ws + OFF_H);
  float* xa   = (float*)(ws + OFF_XA);
  float* nrm  = (float*)(ws + OFF_NORM);
  float* qkv  = (float*)(ws + OFF_QKV);
  float* y    = (float*)(ws + OFF_Y);
  float* h1   = (float*)(ws + OFF_H1);
  float* mlph = (float*)(ws + OFF_MLPH);
  float* adh  = (float*)(ws + OFF_ADH);

  conv1_kernel<<<8000, 256, 0, stream>>>(states, c1_w, c1_b, c1o);
  conv2_kernel<<<4800, 192, 0, stream>>>(c1o, c2_w, c2_b, c2o);
  conv3_kernel<<<1600, 256, 0, stream>>>(c2o, c3_w, c3_b, c3o);
  // state_e = tanh(c3o @ enc_w^T + enc_b): M=1600, N=128, K=3136
  gemm_kernel<1, bf16><<<25*2, 256, 0, stream>>>(c3o, enc_w, enc_b, nullptr, 0.f, se, 1600, 128, 3136);
  token_kernel<<<2400, 256, 0, stream>>>(rtgs, actions, timesteps, ret_w, ret_b, act_tab,
                                         pos_emb, gpe, se, h);

  for (int l = 0; l < 6; ++l){
    const float* g1 = ln_w + (l*3+0)*128; const float* be1 = ln_b + (l*3+0)*128;
    const float* g2 = ln_w + (l*3+1)*128; const float* be2 = ln_b + (l*3+1)*128;
    const float* g3 = ln_w + (l*3+2)*128; const float* be3 = ln_b + (l*3+2)*128;
    // ln1 -> xa, ln3 -> nrm (shared stats)
    ln_kernel<<<1200, 256, 0, stream>>>(h, g1, be1, xa, g3, be3, nrm);
    // k|q|v = xa @ attn_w[l,0..2]^T + b   (N=384)
    gemm_kernel<0, float><<<75*6, 256, 0, stream>>>(xa, attn_w + (size_t)l*4*16384, attn_b + l*4*128,
                                                    nullptr, 0.f, qkv, 4800, 384, 128);
    attn_kernel<<<256, 256, 0, stream>>>(qkv, y);
    // h1 = h + y @ attn_w[l,3]^T + b
    gemm_kernel<0, float><<<75*2, 256, 0, stream>>>(y, attn_w + ((size_t)l*4+3)*16384, attn_b + (l*4+3)*128,
                                                    h, 1.0f, h1, 4800, 128, 128);
    // ln2 -> xa
    ln_kernel<<<1200, 256, 0, stream>>>(h1, g2, be2, xa, nullptr, nullptr, nullptr);
    // mlp hidden = gelu(xa @ w1^T + b1)
    gemm_kernel<2, float><<<75*8, 256, 0, stream>>>(xa, mlp_w1 + (size_t)l*65536, mlp_b1 + l*512,
                                                    nullptr, 0.f, mlph, 4800, 512, 128);
    // adapter hidden = relu(nrm @ dw^T + db)
    gemm_kernel<3, float><<<75*1, 256, 0, stream>>>(nrm, ad_dw + (size_t)l*8192, ad_db + l*64,
                                                    nullptr, 0.f, adh, 4800, 64, 128);
    // h = 2*h1 + mlph @ w2^T + b2
    gemm_kernel<0, float><<<75*2, 256, 0, stream>>>(mlph, mlp_w2 + (size_t)l*65536, mlp_b2 + l*128,
                                                    h1, 2.0f, h, 4800, 128, 512);
    // h += adh @ uw^T + ub
    gemm_kernel<0, float><<<75*2, 256, 0, stream>>>(adh, ad_uw + (size_t)l*8192, ad_ub + l*128,
                                                    h, 1.0f, h, 4800, 128, 64);
  }
  head_kernel<<<1600, 64, 0, stream>>>(h, lnf_w, lnf_b, head_w, out);
}

// Round 4
// 1438.089 us; speedup vs baseline: 2.1580x; 1.4893x over previous
//
#include <hip/hip_runtime.h>
#include <hip/hip_bf16.h>
#include <math.h>

typedef __hip_bfloat16 bf16;

typedef __attribute__((ext_vector_type(8))) short bfrag;
typedef __attribute__((ext_vector_type(4))) float f32x4;
union FragU { bfrag s; uint2 d[2]; unsigned int u[4]; };

static __device__ __forceinline__ float b2f(bf16 x){ return __bfloat162float(x); }
// unpack 2 bf16 packed in a uint32
static __device__ __forceinline__ float2 upk2(unsigned int u){
  union { unsigned int i; float f; } a, b;
  a.i = u << 16;
  b.i = u & 0xffff0000u;
  float2 r; r.x = a.f; r.y = b.f; return r;
}
// pack two floats into a bf16x2 uint
static __device__ __forceinline__ unsigned int f2b2(float lo, float hi){
  bf16 l = __float2bfloat16(lo), h = __float2bfloat16(hi);
  unsigned short lb, hb;
  __builtin_memcpy(&lb, &l, 2); __builtin_memcpy(&hb, &h, 2);
  return (unsigned int)lb | ((unsigned int)hb << 16);
}
static __device__ __forceinline__ void sto(float* p, size_t i, float v){ p[i] = v; }
static __device__ __forceinline__ void sto(bf16* p, size_t i, float v){ p[i] = __float2bfloat16(v); }

// ---------------- workspace layout (bytes) ----------------
constexpr size_t MiB = 1ull << 20;
constexpr size_t OFF_C1   = 0;         // bf16 [1600,32,20,20] 40.96 MB
constexpr size_t OFF_C2   = 41*MiB;    // bf16 [1600,64,9,9]
constexpr size_t OFF_C3   = 58*MiB;    // bf16 [1600,3136]
constexpr size_t OFF_SE   = 69*MiB;    // f32  [1600,128]
constexpr size_t OFF_H    = 0;         // f32  [4800,128]
constexpr size_t OFF_XA   = 3*MiB;     // bf16 [4800,128]
constexpr size_t OFF_NORM = 6*MiB;     // bf16 [4800,128]
constexpr size_t OFF_QKV  = 9*MiB;     // bf16 [4800,384]
constexpr size_t OFF_Y    = 17*MiB;    // bf16 [4800,128]
constexpr size_t OFF_H1   = 20*MiB;    // f32  [4800,128]
constexpr size_t OFF_MLPH = 23*MiB;    // bf16 [4800,512]
constexpr size_t OFF_ADH  = 33*MiB;    // bf16 [4800,64]

// ================= conv1 via implicit-im2col MFMA =================
// x f32 [1600,4,84,84] -> relu -> bf16 [1600,32,20,20]
// GEMM per image: M=400 (oy*20+ox), N=32 (oc), K=256 (c*64+ky*8+kx)
__global__ __launch_bounds__(256) void conv1_kernel(
    const float* __restrict__ x, const float* __restrict__ w,
    const float* __restrict__ bias, bf16* __restrict__ out)
{
  __shared__ bf16 xs1[4*84*88];     // [c][row][88 pad]
  int b = blockIdx.x;
  int t = threadIdx.x;
  const float* xb = x + (size_t)b*28224;
  for (int e = t; e < 28224; e += 256){
    int c = e / 7056, rem = e % 7056;
    int r = rem / 84, col = rem % 84;
    xs1[(c*84 + r)*88 + col] = __float2bfloat16(xb[e]);
  }
  __syncthreads();
  int lane = t & 63, wave = t >> 6;
  int quad = lane >> 4, r16 = lane & 15;
  // wave handles m-tiles wave, wave+4, ... (25 tiles total); n-tiles 0,1
  f32x4 acc[7][2];
  #pragma unroll
  for (int i = 0; i < 7; ++i)
    #pragma unroll
    for (int j = 0; j < 2; ++j) acc[i][j] = (f32x4){0.f,0.f,0.f,0.f};
  int ntile = (25 - wave + 3) / 4;   // 7,6,6,6
  for (int kc = 0; kc < 8; ++kc){
    int c = kc >> 1, ky = (kc & 1)*4 + quad;
    // B fragments (weights) from global, L2-hot: W[oc][k], k contiguous
    FragU bf_[2];
    #pragma unroll
    for (int tn = 0; tn < 2; ++tn){
      int oc = tn*16 + r16;
      const float* wp = w + oc*256 + kc*32 + quad*8;
      float4 wa = ((const float4*)wp)[0], wb = ((const float4*)wp)[1];
      bf_[tn].u[0] = f2b2(wa.x, wa.y); bf_[tn].u[1] = f2b2(wa.z, wa.w);
      bf_[tn].u[2] = f2b2(wb.x, wb.y); bf_[tn].u[3] = f2b2(wb.z, wb.w);
    }
    for (int i = 0; i < ntile; ++i){
      int tile = wave + i*4;
      int m = tile*16 + r16;
      int oy = m / 20, ox = m % 20;
      const bf16* p = xs1 + ((c*84 + 4*oy + ky)*88 + 4*ox);
      FragU a;
      a.d[0] = *(const uint2*)p;
      a.d[1] = *(const uint2*)(p + 4);
      acc[i][0] = __builtin_amdgcn_mfma_f32_16x16x32_bf16(a.s, bf_[0].s, acc[i][0], 0, 0, 0);
      acc[i][1] = __builtin_amdgcn_mfma_f32_16x16x32_bf16(a.s, bf_[1].s, acc[i][1], 0, 0, 0);
    }
  }
  for (int i = 0; i < ntile; ++i){
    int tile = wave + i*4;
    #pragma unroll
    for (int tn = 0; tn < 2; ++tn){
      int oc = tn*16 + r16;
      float bb = bias[oc];
      #pragma unroll
      for (int r = 0; r < 4; ++r){
        int m = tile*16 + quad*4 + r;
        int oy = m / 20, ox = m % 20;
        float v = fmaxf(acc[i][tn][r] + bb, 0.f);
        out[(((size_t)(b*32 + oc)*20 + oy)*20 + ox)] = __float2bfloat16(v);
      }
    }
  }
}

// ================= conv2 via implicit-im2col MFMA =================
// x bf16 [1600,32,20,20] -> relu -> bf16 [1600,64,9,9]
// GEMM per image: M=81 (pad 96), N=64, K=512 (c*16+ky*4+kx)
__global__ __launch_bounds__(256) void conv2_kernel(
    const bf16* __restrict__ x, const float* __restrict__ w,
    const float* __restrict__ bias, bf16* __restrict__ out)
{
  __shared__ bf16 xs2[32*20*24];    // [c][row][24 pad]
  int b = blockIdx.x;
  int t = threadIdx.x;
  const unsigned int* xb = (const unsigned int*)(x + (size_t)b*12800);
  for (int p = t; p < 6400; p += 256){
    int c = p / 200, rem = p % 200;
    int r = rem / 10, cp = rem % 10;
    ((unsigned int*)xs2)[((c*20 + r)*24 + 2*cp) >> 1] = xb[p];
  }
  __syncthreads();
  int lane = t & 63, wave = t >> 6;
  int quad = lane >> 4, r16 = lane & 15;
  int oc = wave*16 + r16;     // wave owns one oc-tile
  f32x4 acc[6];
  #pragma unroll
  for (int i = 0; i < 6; ++i) acc[i] = (f32x4){0.f,0.f,0.f,0.f};
  for (int kc = 0; kc < 16; ++kc){
    // B fragment from global weights (L2-hot), contiguous k
    const float* wp = w + oc*512 + kc*32 + quad*8;
    float4 wa = ((const float4*)wp)[0], wb = ((const float4*)wp)[1];
    FragU bfr;
    bfr.u[0] = f2b2(wa.x, wa.y); bfr.u[1] = f2b2(wa.z, wa.w);
    bfr.u[2] = f2b2(wb.x, wb.y); bfr.u[3] = f2b2(wb.z, wb.w);
    int c = kc*2 + (quad >> 1);
    int ky0 = (quad & 1)*2;
    #pragma unroll
    for (int tile = 0; tile < 6; ++tile){
      int m = tile*16 + r16; if (m > 80) m = 80;
      int oy = m / 9, ox = m % 9;
      int idx1 = (c*20 + 2*oy + ky0)*24 + 2*ox;
      const unsigned int* q1 = (const unsigned int*)(xs2 + idx1);
      const unsigned int* q2 = (const unsigned int*)(xs2 + idx1 + 24);
      FragU a;
      a.u[0] = q1[0]; a.u[1] = q1[1];
      a.u[2] = q2[0]; a.u[3] = q2[1];
      acc[tile] = __builtin_amdgcn_mfma_f32_16x16x32_bf16(a.s, bfr.s, acc[tile], 0, 0, 0);
    }
  }
  float bb = bias[oc];
  #pragma unroll
  for (int tile = 0; tile < 6; ++tile){
    #pragma unroll
    for (int r = 0; r < 4; ++r){
      int m = tile*16 + quad*4 + r;
      if (m < 81){
        int oy = m / 9, ox = m % 9;
        float v = fmaxf(acc[tile][r] + bb, 0.f);
        out[((size_t)(b*64 + oc)*9 + oy)*9 + ox] = __float2bfloat16(v);
      }
    }
  }
}

// ---------------- conv3 (VALU): bf16 [1600,64,9,9] -> relu -> bf16 [1600,3136] ----------------
__global__ __launch_bounds__(256) void conv3_kernel(
    const bf16* __restrict__ x, const float* __restrict__ w,
    const float* __restrict__ bias, bf16* __restrict__ out)
{
  __shared__ float xsf[5184];   // [64][81]
  int b = blockIdx.x;
  int t = threadIdx.x;
  const bf16* xb = x + (size_t)b*5184;
  for (int e = t; e < 2592; e += 256){
    unsigned int u = *(const unsigned int*)(xb + 2*e);
    float2 f = upk2(u);
    xsf[2*e] = f.x; xsf[2*e+1] = f.y;
  }
  __syncthreads();
  int oc = t & 63;
  int oy1 = t >> 6;             // 0..3
  bool two = (t < 192);         // second item: oy1+4
  float a1[7] = {}, a2[7] = {};
  const float* wb3 = w + oc*576;
  for (int c = 0; c < 64; ++c){
    #pragma unroll
    for (int ky = 0; ky < 3; ++ky){
      const float* wp = wb3 + c*9 + ky*3;
      float w0 = wp[0], w1 = wp[1], w2 = wp[2];
      const float* r1 = xsf + c*81 + (oy1+ky)*9;
      #pragma unroll
      for (int ox = 0; ox < 7; ++ox) a1[ox] += r1[ox]*w0 + r1[ox+1]*w1 + r1[ox+2]*w2;
      if (two){
        const float* r2 = xsf + c*81 + (oy1+4+ky)*9;
        #pragma unroll
        for (int ox = 0; ox < 7; ++ox) a2[ox] += r2[ox]*w0 + r2[ox+1]*w1 + r2[ox+2]*w2;
      }
    }
  }
  float bb = bias[oc];
  size_t o1 = (size_t)b*3136 + oc*49 + oy1*7;
  #pragma unroll
  for (int ox = 0; ox < 7; ++ox) out[o1+ox] = __float2bfloat16(fmaxf(a1[ox]+bb, 0.f));
  if (two){
    size_t o2 = (size_t)b*3136 + oc*49 + (oy1+4)*7;
    #pragma unroll
    for (int ox = 0; ox < 7; ++ox) out[o2+ox] = __float2bfloat16(fmaxf(a2[ox]+bb, 0.f));
  }
}

// ================= generic MFMA GEMM =================
// out = ACT(X @ W^T + bias) + add_scale*add;  X bf16 [M,K], W f32 [N,K]
// M%64==0, N%64==0, K%32==0. ACT: 0 none, 1 tanh, 2 gelu, 3 relu. OT: float or bf16.
template<int ACT, typename OT>
__global__ __launch_bounds__(256) void mgemm(
    const bf16* __restrict__ X, const float* __restrict__ W,
    const float* __restrict__ bias, const float* __restrict__ add, float add_scale,
    OT* __restrict__ out, int M, int N, int K)
{
  __shared__ bf16 Xs[64*40];
  __shared__ bf16 Ws[64*40];
  int nb = N >> 6;
  int bn = (blockIdx.x % nb) << 6;
  int bm = (blockIdx.x / nb) << 6;
  int t = threadIdx.x;
  int lane = t & 63, wave = t >> 6;
  int mw = wave >> 1, nw = wave & 1;
  int quad = lane >> 4, r16 = lane & 15;
  int srow = t >> 2, scol = (t & 3)*8;
  f32x4 acc[2][2];
  #pragma unroll
  for (int i = 0; i < 2; ++i)
    #pragma unroll
    for (int j = 0; j < 2; ++j) acc[i][j] = (f32x4){0.f,0.f,0.f,0.f};
  for (int k0 = 0; k0 < K; k0 += 32){
    // stage X (bf16 copy) and W (f32 -> bf16)
    uint4 xv = *(const uint4*)(X + (size_t)(bm + srow)*K + k0 + scol);
    uint2* xd = (uint2*)(Xs + srow*40 + scol);
    xd[0] = make_uint2(xv.x, xv.y); xd[1] = make_uint2(xv.z, xv.w);
    const float* wp = W + (size_t)(bn + srow)*K + k0 + scol;
    float4 wa = ((const float4*)wp)[0], wb = ((const float4*)wp)[1];
    uint2* wd = (uint2*)(Ws + srow*40 + scol);
    wd[0] = make_uint2(f2b2(wa.x, wa.y), f2b2(wa.z, wa.w));
    wd[1] = make_uint2(f2b2(wb.x, wb.y), f2b2(wb.z, wb.w));
    __syncthreads();
    FragU af[2], bf_[2];
    #pragma unroll
    for (int tm = 0; tm < 2; ++tm){
      const bf16* p = Xs + (mw*32 + tm*16 + r16)*40 + quad*8;
      af[tm].d[0] = *(const uint2*)p; af[tm].d[1] = *(const uint2*)(p + 4);
    }
    #pragma unroll
    for (int tn = 0; tn < 2; ++tn){
      const bf16* p = Ws + (nw*32 + tn*16 + r16)*40 + quad*8;
      bf_[tn].d[0] = *(const uint2*)p; bf_[tn].d[1] = *(const uint2*)(p + 4);
    }
    #pragma unroll
    for (int tm = 0; tm < 2; ++tm)
      #pragma unroll
      for (int tn = 0; tn < 2; ++tn)
        acc[tm][tn] = __builtin_amdgcn_mfma_f32_16x16x32_bf16(af[tm].s, bf_[tn].s, acc[tm][tn], 0, 0, 0);
    __syncthreads();
  }
  #pragma unroll
  for (int tm = 0; tm < 2; ++tm){
    #pragma unroll
    for (int tn = 0; tn < 2; ++tn){
      int n = bn + nw*32 + tn*16 + r16;
      float bb = bias[n];
      #pragma unroll
      for (int r = 0; r < 4; ++r){
        int m = bm + mw*32 + tm*16 + quad*4 + r;
        float v = acc[tm][tn][r] + bb;
        if (ACT == 1) v = tanhf(v);
        else if (ACT == 2) v = 0.5f*v*(1.0f + erff(v*0.70710678118f));
        else if (ACT == 3) v = fmaxf(v, 0.f);
        if (add) v += add_scale * add[(size_t)m*N + n];
        sto(out, (size_t)m*N + n, v);
      }
    }
  }
}

// ---------------- token build + pos embedding -> h f32 [4800,128] ----------------
__global__ __launch_bounds__(256) void token_kernel(
    const float* __restrict__ rtgs, const int* __restrict__ actions, const int* __restrict__ timesteps,
    const float* __restrict__ ret_w, const float* __restrict__ ret_b, const float* __restrict__ act_tab,
    const float* __restrict__ pos_emb, const float* __restrict__ gpe,
    const float* __restrict__ se, float* __restrict__ h)
{
  int idx = blockIdx.x*256 + threadIdx.x;   // 4800*128
  int c = idx & 127; int row = idx >> 7;
  int s = row % 150; int b = row / 150;
  int t = s / 3; int r = s - 3*t;
  float tok;
  if (r == 0)      tok = tanhf(rtgs[b*50+t] * ret_w[c] + ret_b[c]);
  else if (r == 1) tok = se[(b*50+t)*128 + c];
  else             tok = tanhf(act_tab[actions[b*50+t]*128 + c]);
  float pe = gpe[(size_t)timesteps[b]*128 + c] + pos_emb[s*128 + c];
  h[idx] = tok + pe;
}

// ---------------- LayerNorm over C=128 -> bf16 outputs ----------------
__global__ __launch_bounds__(256) void ln_kernel(
    const float* __restrict__ x,
    const float* __restrict__ g1, const float* __restrict__ be1, bf16* __restrict__ o1,
    const float* __restrict__ g2, const float* __restrict__ be2, bf16* o2)
{
  int lane = threadIdx.x & 63;
  int row = blockIdx.x*4 + (threadIdx.x >> 6);
  const float2 xv = *(const float2*)(x + (size_t)row*128 + lane*2);
  float s = xv.x + xv.y, sq = xv.x*xv.x + xv.y*xv.y;
  #pragma unroll
  for (int off = 32; off; off >>= 1){ s += __shfl_xor(s, off); sq += __shfl_xor(sq, off); }
  float mean = s * 0.0078125f;
  float var  = sq * 0.0078125f - mean*mean;
  float rstd = rsqrtf(var + 1e-5f);
  float n0 = (xv.x - mean)*rstd, n1 = (xv.y - mean)*rstd;
  int c0 = lane*2;
  ((unsigned int*)o1)[row*64 + lane] = f2b2(n0*g1[c0] + be1[c0], n1*g1[c0+1] + be1[c0+1]);
  if (o2)
    ((unsigned int*)o2)[row*64 + lane] = f2b2(n0*g2[c0] + be2[c0], n1*g2[c0+1] + be2[c0+1]);
}

// ---------------- attention: qkv bf16 [4800,384] (k|q|v), causal, online softmax ----------------
__global__ __launch_bounds__(256) void attn_kernel(const bf16* __restrict__ qkv, bf16* __restrict__ y)
{
  int bh = blockIdx.x;          // 32*8
  int hh = bh & 7; int b = bh >> 3;
  __shared__ float ks[150*16];
  __shared__ float vs[150*16];
  int t = threadIdx.x;
  for (int i = t; i < 2400; i += 256){
    int s = i >> 4; int d = i & 15;
    const bf16* base = qkv + (size_t)(b*150 + s)*384;
    ks[i] = b2f(base[hh*16 + d]);
    vs[i] = b2f(base[256 + hh*16 + d]);
  }
  __syncthreads();
  if (t < 150){
    const bf16* qr = qkv + (size_t)(b*150 + t)*384 + 128 + hh*16;
    float q[16];
    #pragma unroll
    for (int d = 0; d < 16; ++d) q[d] = b2f(qr[d]) * 0.25f;
    float m = -1e30f, l = 0.f, acc[16] = {};
    for (int j = 0; j <= t; ++j){
      const float* kr = ks + j*16;
      float s = 0.f;
      #pragma unroll
      for (int d = 0; d < 16; ++d) s += q[d]*kr[d];
      float mn = fmaxf(m, s);
      float corr = __expf(m - mn);
      float p = __expf(s - mn);
      l = l*corr + p;
      const float* vr = vs + j*16;
      #pragma unroll
      for (int d = 0; d < 16; ++d) acc[d] = acc[d]*corr + p*vr[d];
      m = mn;
    }
    float inv = 1.f / l;
    bf16* yr = y + (size_t)(b*150 + t)*128 + hh*16;
    #pragma unroll
    for (int d = 0; d < 16; ++d) yr[d] = __float2bfloat16(acc[d]*inv);
  }
}

// ---------------- fused final LN + head on state tokens -> f32 [1600,18] ----------------
__global__ __launch_bounds__(64) void head_kernel(
    const float* __restrict__ h, const float* __restrict__ g, const float* __restrict__ be,
    const float* __restrict__ hw, float* __restrict__ out)
{
  int bt = blockIdx.x;
  int lane = threadIdx.x;
  int b = bt / 50, t = bt % 50;
  const float* row = h + ((size_t)b*150 + 3*t + 1)*128;
  float2 xv = *(const float2*)(row + lane*2);
  float s = xv.x + xv.y, sq = xv.x*xv.x + xv.y*xv.y;
  #pragma unroll
  for (int off = 32; off; off >>= 1){ s += __shfl_xor(s, off); sq += __shfl_xor(sq, off); }
  float mean = s * 0.0078125f;
  float var  = sq * 0.0078125f - mean*mean;
  float rstd = rsqrtf(var + 1e-5f);
  int c0 = lane*2;
  __shared__ float sh[128];
  sh[c0]   = (xv.x-mean)*rstd*g[c0]   + be[c0];
  sh[c0+1] = (xv.y-mean)*rstd*g[c0+1] + be[c0+1];
  __syncthreads();
  if (lane < 18){
    const float* wr = hw + lane*128;
    float acc = 0.f;
    #pragma unroll
    for (int c = 0; c < 128; c += 4){
      float4 wf = *(const float4*)(wr + c);
      acc += sh[c]*wf.x + sh[c+1]*wf.y + sh[c+2]*wf.z + sh[c+3]*wf.w;
    }
    out[bt*18 + lane] = acc;
  }
}

// ---------------- launch ----------------
extern "C" void kernel_launch(void* const* d_in, const int* in_sizes, int n_in,
                              void* d_out, int out_size, void* d_ws, size_t ws_size,
                              hipStream_t stream)
{
  const float* states    = (const float*)d_in[0];
  const float* rtgs      = (const float*)d_in[1];
  const int*   actions   = (const int*)d_in[2];
  const int*   timesteps = (const int*)d_in[3];
  const float* pos_emb   = (const float*)d_in[5];
  const float* gpe       = (const float*)d_in[6];
  const float* c1_w = (const float*)d_in[7];  const float* c1_b = (const float*)d_in[8];
  const float* c2_w = (const float*)d_in[9];  const float* c2_b = (const float*)d_in[10];
  const float* c3_w = (const float*)d_in[11]; const float* c3_b = (const float*)d_in[12];
  const float* enc_w = (const float*)d_in[13]; const float* enc_b = (const float*)d_in[14];
  const float* ret_w = (const float*)d_in[15]; const float* ret_b = (const float*)d_in[16];
  const float* act_tab = (const float*)d_in[17];
  const float* ln_w = (const float*)d_in[18]; const float* ln_b = (const float*)d_in[19];
  const float* attn_w = (const float*)d_in[20]; const float* attn_b = (const float*)d_in[21];
  const float* mlp_w1 = (const float*)d_in[22]; const float* mlp_b1 = (const float*)d_in[23];
  const float* mlp_w2 = (const float*)d_in[24]; const float* mlp_b2 = (const float*)d_in[25];
  const float* ad_dw = (const float*)d_in[26]; const float* ad_db = (const float*)d_in[27];
  const float* ad_uw = (const float*)d_in[28]; const float* ad_ub = (const float*)d_in[29];
  const float* lnf_w = (const float*)d_in[30]; const float* lnf_b = (const float*)d_in[31];
  const float* head_w = (const float*)d_in[32];
  float* out = (float*)d_out;

  char* ws = (char*)d_ws;
  bf16* c1o  = (bf16*)(ws + OFF_C1);
  bf16* c2o  = (bf16*)(ws + OFF_C2);
  bf16* c3o  = (bf16*)(ws + OFF_C3);
  float* se  = (float*)(ws + OFF_SE);
  float* h   = (float*)(ws + OFF_H);
  bf16* xa   = (bf16*)(ws + OFF_XA);
  bf16* nrm  = (bf16*)(ws + OFF_NORM);
  bf16* qkv  = (bf16*)(ws + OFF_QKV);
  bf16* y    = (bf16*)(ws + OFF_Y);
  float* h1  = (float*)(ws + OFF_H1);
  bf16* mlph = (bf16*)(ws + OFF_MLPH);
  bf16* adh  = (bf16*)(ws + OFF_ADH);

  conv1_kernel<<<1600, 256, 0, stream>>>(states, c1_w, c1_b, c1o);
  conv2_kernel<<<1600, 256, 0, stream>>>(c1o, c2_w, c2_b, c2o);
  conv3_kernel<<<1600, 256, 0, stream>>>(c2o, c3_w, c3_b, c3o);
  // state_e = tanh(c3o @ enc_w^T + enc_b): M=1600, N=128, K=3136
  mgemm<1, float><<<25*2, 256, 0, stream>>>(c3o, enc_w, enc_b, nullptr, 0.f, se, 1600, 128, 3136);
  token_kernel<<<2400, 256, 0, stream>>>(rtgs, actions, timesteps, ret_w, ret_b, act_tab,
                                         pos_emb, gpe, se, h);

  for (int l = 0; l < 6; ++l){
    const float* g1 = ln_w + (l*3+0)*128; const float* be1 = ln_b + (l*3+0)*128;
    const float* g2 = ln_w + (l*3+1)*128; const float* be2 = ln_b + (l*3+1)*128;
    const float* g3 = ln_w + (l*3+2)*128; const float* be3 = ln_b + (l*3+2)*128;
    ln_kernel<<<1200, 256, 0, stream>>>(h, g1, be1, xa, g3, be3, nrm);
    mgemm<0, bf16><<<75*6, 256, 0, stream>>>(xa, attn_w + (size_t)l*4*16384, attn_b + l*4*128,
                                             nullptr, 0.f, qkv, 4800, 384, 128);
    attn_kernel<<<256, 256, 0, stream>>>(qkv, y);
    mgemm<0, float><<<75*2, 256, 0, stream>>>(y, attn_w + ((size_t)l*4+3)*16384, attn_b + (l*4+3)*128,
                                              h, 1.0f, h1, 4800, 128, 128);
    ln_kernel<<<1200, 256, 0, stream>>>(h1, g2, be2, xa, nullptr, nullptr, nullptr);
    mgemm<2, bf16><<<75*8, 256, 0, stream>>>(xa, mlp_w1 + (size_t)l*65536, mlp_b1 + l*512,
                                             nullptr, 0.f, mlph, 4800, 512, 128);
    mgemm<3, bf16><<<75*1, 256, 0, stream>>>(nrm, ad_dw + (size_t)l*8192, ad_db + l*64,
                                             nullptr, 0.f, adh, 4800, 64, 128);
    mgemm<0, float><<<75*2, 256, 0, stream>>>(mlph, mlp_w2 + (size_t)l*65536, mlp_b2 + l*128,
                                              h1, 2.0f, h, 4800, 128, 512);
    mgemm<0, float><<<75*2, 256, 0, stream>>>(adh, ad_uw + (size_t)l*8192, ad_ub + l*128,
                                              h, 1.0f, h, 4800, 128, 64);
  }
  head_kernel<<<1600, 64, 0, stream>>>(h, lnf_w, lnf_b, head_w, out);
}

// Round 5
// 1401.873 us; speedup vs baseline: 2.2137x; 1.0258x over previous
//
#include <hip/hip_runtime.h>
#include <hip/hip_bf16.h>
#include <math.h>

typedef __hip_bfloat16 bf16;

typedef __attribute__((ext_vector_type(8))) short bfrag;
typedef __attribute__((ext_vector_type(4))) float f32x4;
union FragU { bfrag s; uint2 d[2]; unsigned int u[4]; };

static __device__ __forceinline__ float b2f(bf16 x){ return __bfloat162float(x); }
// unpack 2 bf16 packed in a uint32
static __device__ __forceinline__ float2 upk2(unsigned int u){
  union { unsigned int i; float f; } a, b;
  a.i = u << 16;
  b.i = u & 0xffff0000u;
  float2 r; r.x = a.f; r.y = b.f; return r;
}
// pack two floats into a bf16x2 uint
static __device__ __forceinline__ unsigned int f2b2(float lo, float hi){
  bf16 l = __float2bfloat16(lo), h = __float2bfloat16(hi);
  unsigned short lb, hb;
  __builtin_memcpy(&lb, &l, 2); __builtin_memcpy(&hb, &h, 2);
  return (unsigned int)lb | ((unsigned int)hb << 16);
}
static __device__ __forceinline__ void sto(float* p, size_t i, float v){ p[i] = v; }
static __device__ __forceinline__ void sto(bf16* p, size_t i, float v){ p[i] = __float2bfloat16(v); }

// ---------------- workspace layout (bytes) ----------------
constexpr size_t MiB = 1ull << 20;
constexpr size_t OFF_C1   = 0;         // bf16 [1600,32,20,20] 40.96 MB
constexpr size_t OFF_C2   = 41*MiB;    // bf16 [1600,64,9,9]
constexpr size_t OFF_C3   = 58*MiB;    // bf16 [1600,3136]
constexpr size_t OFF_SE   = 69*MiB;    // f32  [1600,128]
constexpr size_t OFF_H    = 0;         // f32  [4800,128]
constexpr size_t OFF_XA   = 3*MiB;     // bf16 [4800,128]
constexpr size_t OFF_NORM = 6*MiB;     // bf16 [4800,128]
constexpr size_t OFF_QKV  = 9*MiB;     // bf16 [4800,384]
constexpr size_t OFF_Y    = 17*MiB;    // bf16 [4800,128]
constexpr size_t OFF_H1   = 20*MiB;    // f32  [4800,128]
constexpr size_t OFF_MLPH = 23*MiB;    // bf16 [4800,512]
constexpr size_t OFF_ADH  = 33*MiB;    // bf16 [4800,64]

// ================= conv1 via implicit-im2col MFMA =================
// x f32 [1600,4,84,84] -> relu -> bf16 [1600,32,20,20]
// GEMM per image: M=400 (oy*20+ox), N=32 (oc), K=256 (c*64+ky*8+kx)
// Output restaged through LDS for coalesced uint4 stores (write-amp fix).
__global__ __launch_bounds__(256) void conv1_kernel(
    const float* __restrict__ x, const float* __restrict__ w,
    const float* __restrict__ bias, bf16* __restrict__ out)
{
  __shared__ bf16 xs1[4*84*88];     // [c][row][88 pad]; reused as out-stage [32][408]
  int b = blockIdx.x;
  int t = threadIdx.x;
  const float* xb = x + (size_t)b*28224;
  for (int e = t; e < 28224; e += 256){
    int c = e / 7056, rem = e % 7056;
    int r = rem / 84, col = rem % 84;
    xs1[(c*84 + r)*88 + col] = __float2bfloat16(xb[e]);
  }
  __syncthreads();
  int lane = t & 63, wave = t >> 6;
  int quad = lane >> 4, r16 = lane & 15;
  f32x4 acc[7][2];
  #pragma unroll
  for (int i = 0; i < 7; ++i)
    #pragma unroll
    for (int j = 0; j < 2; ++j) acc[i][j] = (f32x4){0.f,0.f,0.f,0.f};
  int ntile = (25 - wave + 3) / 4;   // 7,6,6,6
  for (int kc = 0; kc < 8; ++kc){
    int c = kc >> 1, ky = (kc & 1)*4 + quad;
    FragU bf_[2];
    #pragma unroll
    for (int tn = 0; tn < 2; ++tn){
      int oc = tn*16 + r16;
      const float* wp = w + oc*256 + kc*32 + quad*8;
      float4 wa = ((const float4*)wp)[0], wb = ((const float4*)wp)[1];
      bf_[tn].u[0] = f2b2(wa.x, wa.y); bf_[tn].u[1] = f2b2(wa.z, wa.w);
      bf_[tn].u[2] = f2b2(wb.x, wb.y); bf_[tn].u[3] = f2b2(wb.z, wb.w);
    }
    for (int i = 0; i < ntile; ++i){
      int tile = wave + i*4;
      int m = tile*16 + r16;
      int oy = m / 20, ox = m % 20;
      const bf16* p = xs1 + ((c*84 + 4*oy + ky)*88 + 4*ox);
      FragU a;
      a.d[0] = *(const uint2*)p;
      a.d[1] = *(const uint2*)(p + 4);
      acc[i][0] = __builtin_amdgcn_mfma_f32_16x16x32_bf16(a.s, bf_[0].s, acc[i][0], 0, 0, 0);
      acc[i][1] = __builtin_amdgcn_mfma_f32_16x16x32_bf16(a.s, bf_[1].s, acc[i][1], 0, 0, 0);
    }
  }
  __syncthreads();   // input staging reads done; reuse xs1 as output stage [32][408]
  for (int i = 0; i < ntile; ++i){
    int tile = wave + i*4;
    int m0 = tile*16 + quad*4;
    #pragma unroll
    for (int tn = 0; tn < 2; ++tn){
      int oc = tn*16 + r16;
      float bb = bias[oc];
      float v0 = fmaxf(acc[i][tn][0] + bb, 0.f);
      float v1 = fmaxf(acc[i][tn][1] + bb, 0.f);
      float v2 = fmaxf(acc[i][tn][2] + bb, 0.f);
      float v3 = fmaxf(acc[i][tn][3] + bb, 0.f);
      *(uint2*)(xs1 + oc*408 + m0) = make_uint2(f2b2(v0, v1), f2b2(v2, v3));
    }
  }
  __syncthreads();
  bf16* outp = out + (size_t)b*12800;
  for (int e = t; e < 1600; e += 256){
    int oc = e / 50, col = e % 50;
    uint4 v = *(const uint4*)(xs1 + oc*408 + col*8);
    *(uint4*)(outp + oc*400 + col*8) = v;
  }
}

// ================= conv2 via implicit-im2col MFMA =================
// x bf16 [1600,32,20,20] -> relu -> bf16 [1600,64,9,9]
// GEMM per image: M=81 (pad 96), N=64, K=512 (c*16+ky*4+kx)
// Output restaged through LDS in exact out layout for coalesced uint stores.
__global__ __launch_bounds__(256) void conv2_kernel(
    const bf16* __restrict__ x, const float* __restrict__ w,
    const float* __restrict__ bias, bf16* __restrict__ out)
{
  __shared__ bf16 xs2[32*20*24];    // [c][row][24 pad]; reused as out-stage [64][81]
  int b = blockIdx.x;
  int t = threadIdx.x;
  const unsigned int* xb = (const unsigned int*)(x + (size_t)b*12800);
  for (int p = t; p < 6400; p += 256){
    int c = p / 200, rem = p % 200;
    int r = rem / 10, cp = rem % 10;
    ((unsigned int*)xs2)[((c*20 + r)*24 + 2*cp) >> 1] = xb[p];
  }
  __syncthreads();
  int lane = t & 63, wave = t >> 6;
  int quad = lane >> 4, r16 = lane & 15;
  int oc = wave*16 + r16;     // wave owns one oc-tile
  f32x4 acc[6];
  #pragma unroll
  for (int i = 0; i < 6; ++i) acc[i] = (f32x4){0.f,0.f,0.f,0.f};
  for (int kc = 0; kc < 16; ++kc){
    const float* wp = w + oc*512 + kc*32 + quad*8;
    float4 wa = ((const float4*)wp)[0], wb = ((const float4*)wp)[1];
    FragU bfr;
    bfr.u[0] = f2b2(wa.x, wa.y); bfr.u[1] = f2b2(wa.z, wa.w);
    bfr.u[2] = f2b2(wb.x, wb.y); bfr.u[3] = f2b2(wb.z, wb.w);
    int c = kc*2 + (quad >> 1);
    int ky0 = (quad & 1)*2;
    #pragma unroll
    for (int tile = 0; tile < 6; ++tile){
      int m = tile*16 + r16; if (m > 80) m = 80;
      int oy = m / 9, ox = m % 9;
      int idx1 = (c*20 + 2*oy + ky0)*24 + 2*ox;
      const unsigned int* q1 = (const unsigned int*)(xs2 + idx1);
      const unsigned int* q2 = (const unsigned int*)(xs2 + idx1 + 24);
      FragU a;
      a.u[0] = q1[0]; a.u[1] = q1[1];
      a.u[2] = q2[0]; a.u[3] = q2[1];
      acc[tile] = __builtin_amdgcn_mfma_f32_16x16x32_bf16(a.s, bfr.s, acc[tile], 0, 0, 0);
    }
  }
  __syncthreads();   // staging reads done; reuse xs2 as out-stage [64][81]
  float bb = bias[oc];
  #pragma unroll
  for (int tile = 0; tile < 6; ++tile){
    #pragma unroll
    for (int r = 0; r < 4; ++r){
      int m = tile*16 + quad*4 + r;
      if (m < 81){
        float v = fmaxf(acc[tile][r] + bb, 0.f);
        xs2[oc*81 + m] = __float2bfloat16(v);
      }
    }
  }
  __syncthreads();
  const unsigned int* lsu = (const unsigned int*)xs2;
  unsigned int* op = (unsigned int*)(out + (size_t)b*5184);
  for (int e = t; e < 2592; e += 256) op[e] = lsu[e];
}

// ---------------- conv3 (VALU): bf16 [1600,64,9,9] -> relu -> bf16 [1600,3136] ----------------
__global__ __launch_bounds__(256) void conv3_kernel(
    const bf16* __restrict__ x, const float* __restrict__ w,
    const float* __restrict__ bias, bf16* __restrict__ out)
{
  __shared__ float xsf[5184];   // [64][81]
  int b = blockIdx.x;
  int t = threadIdx.x;
  const bf16* xb = x + (size_t)b*5184;
  for (int e = t; e < 2592; e += 256){
    unsigned int u = *(const unsigned int*)(xb + 2*e);
    float2 f = upk2(u);
    xsf[2*e] = f.x; xsf[2*e+1] = f.y;
  }
  __syncthreads();
  int oc = t & 63;
  int oy1 = t >> 6;             // 0..3
  bool two = (t < 192);         // second item: oy1+4
  float a1[7] = {}, a2[7] = {};
  const float* wb3 = w + oc*576;
  for (int c = 0; c < 64; ++c){
    #pragma unroll
    for (int ky = 0; ky < 3; ++ky){
      const float* wp = wb3 + c*9 + ky*3;
      float w0 = wp[0], w1 = wp[1], w2 = wp[2];
      const float* r1 = xsf + c*81 + (oy1+ky)*9;
      #pragma unroll
      for (int ox = 0; ox < 7; ++ox) a1[ox] += r1[ox]*w0 + r1[ox+1]*w1 + r1[ox+2]*w2;
      if (two){
        const float* r2 = xsf + c*81 + (oy1+4+ky)*9;
        #pragma unroll
        for (int ox = 0; ox < 7; ++ox) a2[ox] += r2[ox]*w0 + r2[ox+1]*w1 + r2[ox+2]*w2;
      }
    }
  }
  float bb = bias[oc];
  size_t o1 = (size_t)b*3136 + oc*49 + oy1*7;
  #pragma unroll
  for (int ox = 0; ox < 7; ++ox) out[o1+ox] = __float2bfloat16(fmaxf(a1[ox]+bb, 0.f));
  if (two){
    size_t o2 = (size_t)b*3136 + oc*49 + (oy1+4)*7;
    #pragma unroll
    for (int ox = 0; ox < 7; ++ox) out[o2+ox] = __float2bfloat16(fmaxf(a2[ox]+bb, 0.f));
  }
}

// ================= generic MFMA GEMM =================
// out = ACT(X @ W^T + bias) + add_scale*add;  X bf16 [M,K], W f32 [N,K]
// M%64==0, N%64==0, K%32==0. ACT: 0 none, 1 tanh, 2 gelu, 3 relu. OT: float or bf16.
template<int ACT, typename OT>
__global__ __launch_bounds__(256) void mgemm(
    const bf16* __restrict__ X, const float* __restrict__ W,
    const float* __restrict__ bias, const float* __restrict__ add, float add_scale,
    OT* __restrict__ out, int M, int N, int K)
{
  __shared__ bf16 Xs[64*40];
  __shared__ bf16 Ws[64*40];
  int nb = N >> 6;
  int bn = (blockIdx.x % nb) << 6;
  int bm = (blockIdx.x / nb) << 6;
  int t = threadIdx.x;
  int lane = t & 63, wave = t >> 6;
  int mw = wave >> 1, nw = wave & 1;
  int quad = lane >> 4, r16 = lane & 15;
  int srow = t >> 2, scol = (t & 3)*8;
  f32x4 acc[2][2];
  #pragma unroll
  for (int i = 0; i < 2; ++i)
    #pragma unroll
    for (int j = 0; j < 2; ++j) acc[i][j] = (f32x4){0.f,0.f,0.f,0.f};
  for (int k0 = 0; k0 < K; k0 += 32){
    uint4 xv = *(const uint4*)(X + (size_t)(bm + srow)*K + k0 + scol);
    uint2* xd = (uint2*)(Xs + srow*40 + scol);
    xd[0] = make_uint2(xv.x, xv.y); xd[1] = make_uint2(xv.z, xv.w);
    const float* wp = W + (size_t)(bn + srow)*K + k0 + scol;
    float4 wa = ((const float4*)wp)[0], wb = ((const float4*)wp)[1];
    uint2* wd = (uint2*)(Ws + srow*40 + scol);
    wd[0] = make_uint2(f2b2(wa.x, wa.y), f2b2(wa.z, wa.w));
    wd[1] = make_uint2(f2b2(wb.x, wb.y), f2b2(wb.z, wb.w));
    __syncthreads();
    FragU af[2], bf_[2];
    #pragma unroll
    for (int tm = 0; tm < 2; ++tm){
      const bf16* p = Xs + (mw*32 + tm*16 + r16)*40 + quad*8;
      af[tm].d[0] = *(const uint2*)p; af[tm].d[1] = *(const uint2*)(p + 4);
    }
    #pragma unroll
    for (int tn = 0; tn < 2; ++tn){
      const bf16* p = Ws + (nw*32 + tn*16 + r16)*40 + quad*8;
      bf_[tn].d[0] = *(const uint2*)p; bf_[tn].d[1] = *(const uint2*)(p + 4);
    }
    #pragma unroll
    for (int tm = 0; tm < 2; ++tm)
      #pragma unroll
      for (int tn = 0; tn < 2; ++tn)
        acc[tm][tn] = __builtin_amdgcn_mfma_f32_16x16x32_bf16(af[tm].s, bf_[tn].s, acc[tm][tn], 0, 0, 0);
    __syncthreads();
  }
  #pragma unroll
  for (int tm = 0; tm < 2; ++tm){
    #pragma unroll
    for (int tn = 0; tn < 2; ++tn){
      int n = bn + nw*32 + tn*16 + r16;
      float bb = bias[n];
      #pragma unroll
      for (int r = 0; r < 4; ++r){
        int m = bm + mw*32 + tm*16 + quad*4 + r;
        float v = acc[tm][tn][r] + bb;
        if (ACT == 1) v = tanhf(v);
        else if (ACT == 2) v = 0.5f*v*(1.0f + erff(v*0.70710678118f));
        else if (ACT == 3) v = fmaxf(v, 0.f);
        if (add) v += add_scale * add[(size_t)m*N + n];
        sto(out, (size_t)m*N + n, v);
      }
    }
  }
}

// ---------------- token build + pos embedding -> h f32 [4800,128] ----------------
__global__ __launch_bounds__(256) void token_kernel(
    const float* __restrict__ rtgs, const int* __restrict__ actions, const int* __restrict__ timesteps,
    const float* __restrict__ ret_w, const float* __restrict__ ret_b, const float* __restrict__ act_tab,
    const float* __restrict__ pos_emb, const float* __restrict__ gpe,
    const float* __restrict__ se, float* __restrict__ h)
{
  int idx = blockIdx.x*256 + threadIdx.x;   // 4800*128
  int c = idx & 127; int row = idx >> 7;
  int s = row % 150; int b = row / 150;
  int t = s / 3; int r = s - 3*t;
  float tok;
  if (r == 0)      tok = tanhf(rtgs[b*50+t] * ret_w[c] + ret_b[c]);
  else if (r == 1) tok = se[(b*50+t)*128 + c];
  else             tok = tanhf(act_tab[actions[b*50+t]*128 + c]);
  float pe = gpe[(size_t)timesteps[b]*128 + c] + pos_emb[s*128 + c];
  h[idx] = tok + pe;
}

// ---------------- LayerNorm over C=128 -> bf16 outputs ----------------
__global__ __launch_bounds__(256) void ln_kernel(
    const float* __restrict__ x,
    const float* __restrict__ g1, const float* __restrict__ be1, bf16* __restrict__ o1,
    const float* __restrict__ g2, const float* __restrict__ be2, bf16* o2)
{
  int lane = threadIdx.x & 63;
  int row = blockIdx.x*4 + (threadIdx.x >> 6);
  const float2 xv = *(const float2*)(x + (size_t)row*128 + lane*2);
  float s = xv.x + xv.y, sq = xv.x*xv.x + xv.y*xv.y;
  #pragma unroll
  for (int off = 32; off; off >>= 1){ s += __shfl_xor(s, off); sq += __shfl_xor(sq, off); }
  float mean = s * 0.0078125f;
  float var  = sq * 0.0078125f - mean*mean;
  float rstd = rsqrtf(var + 1e-5f);
  float n0 = (xv.x - mean)*rstd, n1 = (xv.y - mean)*rstd;
  int c0 = lane*2;
  ((unsigned int*)o1)[row*64 + lane] = f2b2(n0*g1[c0] + be1[c0], n1*g1[c0+1] + be1[c0+1]);
  if (o2)
    ((unsigned int*)o2)[row*64 + lane] = f2b2(n0*g2[c0] + be2[c0], n1*g2[c0+1] + be2[c0+1]);
}

// ---------------- attention: qkv bf16 [4800,384] (k|q|v), causal, online softmax ----------------
__global__ __launch_bounds__(256) void attn_kernel(const bf16* __restrict__ qkv, bf16* __restrict__ y)
{
  int bh = blockIdx.x;          // 32*8
  int hh = bh & 7; int b = bh >> 3;
  __shared__ float ks[150*16];
  __shared__ float vs[150*16];
  int t = threadIdx.x;
  for (int i = t; i < 2400; i += 256){
    int s = i >> 4; int d = i & 15;
    const bf16* base = qkv + (size_t)(b*150 + s)*384;
    ks[i] = b2f(base[hh*16 + d]);
    vs[i] = b2f(base[256 + hh*16 + d]);
  }
  __syncthreads();
  if (t < 150){
    const bf16* qr = qkv + (size_t)(b*150 + t)*384 + 128 + hh*16;
    float q[16];
    #pragma unroll
    for (int d = 0; d < 16; ++d) q[d] = b2f(qr[d]) * 0.25f;
    float m = -1e30f, l = 0.f, acc[16] = {};
    for (int j = 0; j <= t; ++j){
      const float* kr = ks + j*16;
      float s = 0.f;
      #pragma unroll
      for (int d = 0; d < 16; ++d) s += q[d]*kr[d];
      float mn = fmaxf(m, s);
      float corr = __expf(m - mn);
      float p = __expf(s - mn);
      l = l*corr + p;
      const float* vr = vs + j*16;
      #pragma unroll
      for (int d = 0; d < 16; ++d) acc[d] = acc[d]*corr + p*vr[d];
      m = mn;
    }
    float inv = 1.f / l;
    bf16* yr = y + (size_t)(b*150 + t)*128 + hh*16;
    #pragma unroll
    for (int d = 0; d < 16; ++d) yr[d] = __float2bfloat16(acc[d]*inv);
  }
}

// ---------------- fused final LN + head on state tokens -> f32 [1600,18] ----------------
__global__ __launch_bounds__(64) void head_kernel(
    const float* __restrict__ h, const float* __restrict__ g, const float* __restrict__ be,
    const float* __restrict__ hw, float* __restrict__ out)
{
  int bt = blockIdx.x;
  int lane = threadIdx.x;
  int b = bt / 50, t = bt % 50;
  const float* row = h + ((size_t)b*150 + 3*t + 1)*128;
  float2 xv = *(const float2*)(row + lane*2);
  float s = xv.x + xv.y, sq = xv.x*xv.x + xv.y*xv.y;
  #pragma unroll
  for (int off = 32; off; off >>= 1){ s += __shfl_xor(s, off); sq += __shfl_xor(sq, off); }
  float mean = s * 0.0078125f;
  float var  = sq * 0.0078125f - mean*mean;
  float rstd = rsqrtf(var + 1e-5f);
  int c0 = lane*2;
  __shared__ float sh[128];
  sh[c0]   = (xv.x-mean)*rstd*g[c0]   + be[c0];
  sh[c0+1] = (xv.y-mean)*rstd*g[c0+1] + be[c0+1];
  __syncthreads();
  if (lane < 18){
    const float* wr = hw + lane*128;
    float acc = 0.f;
    #pragma unroll
    for (int c = 0; c < 128; c += 4){
      float4 wf = *(const float4*)(wr + c);
      acc += sh[c]*wf.x + sh[c+1]*wf.y + sh[c+2]*wf.z + sh[c+3]*wf.w;
    }
    out[bt*18 + lane] = acc;
  }
}

// ---------------- launch ----------------
extern "C" void kernel_launch(void* const* d_in, const int* in_sizes, int n_in,
                              void* d_out, int out_size, void* d_ws, size_t ws_size,
                              hipStream_t stream)
{
  const float* states    = (const float*)d_in[0];
  const float* rtgs      = (const float*)d_in[1];
  const int*   actions   = (const int*)d_in[2];
  const int*   timesteps = (const int*)d_in[3];
  const float* pos_emb   = (const float*)d_in[5];
  const float* gpe       = (const float*)d_in[6];
  const float* c1_w = (const float*)d_in[7];  const float* c1_b = (const float*)d_in[8];
  const float* c2_w = (const float*)d_in[9];  const float* c2_b = (const float*)d_in[10];
  const float* c3_w = (const float*)d_in[11]; const float* c3_b = (const float*)d_in[12];
  const float* enc_w = (const float*)d_in[13]; const float* enc_b = (const float*)d_in[14];
  const float* ret_w = (const float*)d_in[15]; const float* ret_b = (const float*)d_in[16];
  const float* act_tab = (const float*)d_in[17];
  const float* ln_w = (const float*)d_in[18]; const float* ln_b = (const float*)d_in[19];
  const float* attn_w = (const float*)d_in[20]; const float* attn_b = (const float*)d_in[21];
  const float* mlp_w1 = (const float*)d_in[22]; const float* mlp_b1 = (const float*)d_in[23];
  const float* mlp_w2 = (const float*)d_in[24]; const float* mlp_b2 = (const float*)d_in[25];
  const float* ad_dw = (const float*)d_in[26]; const float* ad_db = (const float*)d_in[27];
  const float* ad_uw = (const float*)d_in[28]; const float* ad_ub = (const float*)d_in[29];
  const float* lnf_w = (const float*)d_in[30]; const float* lnf_b = (const float*)d_in[31];
  const float* head_w = (const float*)d_in[32];
  float* out = (float*)d_out;

  char* ws = (char*)d_ws;
  bf16* c1o  = (bf16*)(ws + OFF_C1);
  bf16* c2o  = (bf16*)(ws + OFF_C2);
  bf16* c3o  = (bf16*)(ws + OFF_C3);
  float* se  = (float*)(ws + OFF_SE);
  float* h   = (float*)(ws + OFF_H);
  bf16* xa   = (bf16*)(ws + OFF_XA);
  bf16* nrm  = (bf16*)(ws + OFF_NORM);
  bf16* qkv  = (bf16*)(ws + OFF_QKV);
  bf16* y    = (bf16*)(ws + OFF_Y);
  float* h1  = (float*)(ws + OFF_H1);
  bf16* mlph = (bf16*)(ws + OFF_MLPH);
  bf16* adh  = (bf16*)(ws + OFF_ADH);

  conv1_kernel<<<1600, 256, 0, stream>>>(states, c1_w, c1_b, c1o);
  conv2_kernel<<<1600, 256, 0, stream>>>(c1o, c2_w, c2_b, c2o);
  conv3_kernel<<<1600, 256, 0, stream>>>(c2o, c3_w, c3_b, c3o);
  // state_e = tanh(c3o @ enc_w^T + enc_b): M=1600, N=128, K=3136
  mgemm<1, float><<<25*2, 256, 0, stream>>>(c3o, enc_w, enc_b, nullptr, 0.f, se, 1600, 128, 3136);
  token_kernel<<<2400, 256, 0, stream>>>(rtgs, actions, timesteps, ret_w, ret_b, act_tab,
                                         pos_emb, gpe, se, h);

  for (int l = 0; l < 6; ++l){
    const float* g1 = ln_w + (l*3+0)*128; const float* be1 = ln_b + (l*3+0)*128;
    const float* g2 = ln_w + (l*3+1)*128; const float* be2 = ln_b + (l*3+1)*128;
    const float* g3 = ln_w + (l*3+2)*128; const float* be3 = ln_b + (l*3+2)*128;
    ln_kernel<<<1200, 256, 0, stream>>>(h, g1, be1, xa, g3, be3, nrm);
    mgemm<0, bf16><<<75*6, 256, 0, stream>>>(xa, attn_w + (size_t)l*4*16384, attn_b + l*4*128,
                                             nullptr, 0.f, qkv, 4800, 384, 128);
    attn_kernel<<<256, 256, 0, stream>>>(qkv, y);
    mgemm<0, float><<<75*2, 256, 0, stream>>>(y, attn_w + ((size_t)l*4+3)*16384, attn_b + (l*4+3)*128,
                                              h, 1.0f, h1, 4800, 128, 128);
    ln_kernel<<<1200, 256, 0, stream>>>(h1, g2, be2, xa, nullptr, nullptr, nullptr);
    mgemm<2, bf16><<<75*8, 256, 0, stream>>>(xa, mlp_w1 + (size_t)l*65536, mlp_b1 + l*512,
                                             nullptr, 0.f, mlph, 4800, 512, 128);
    mgemm<3, bf16><<<75*1, 256, 0, stream>>>(nrm, ad_dw + (size_t)l*8192, ad_db + l*64,
                                             nullptr, 0.f, adh, 4800, 64, 128);
    mgemm<0, float><<<75*2, 256, 0, stream>>>(mlph, mlp_w2 + (size_t)l*65536, mlp_b2 + l*128,
                                              h1, 2.0f, h, 4800, 128, 512);
    mgemm<0, float><<<75*2, 256, 0, stream>>>(adh, ad_uw + (size_t)l*8192, ad_ub + l*128,
                                              h, 1.0f, h, 4800, 128, 64);
  }
  head_kernel<<<1600, 64, 0, stream>>>(h, lnf_w, lnf_b, head_w, out);
}

// Round 6
// 1242.725 us; speedup vs baseline: 2.4972x; 1.1281x over previous
//
#include <hip/hip_runtime.h>
#include <hip/hip_bf16.h>
#include <math.h>

typedef __hip_bfloat16 bf16;

typedef __attribute__((ext_vector_type(8))) short bfrag;
typedef __attribute__((ext_vector_type(4))) float f32x4;
union FragU { bfrag s; uint2 d[2]; unsigned int u[4]; };

static __device__ __forceinline__ float b2f(bf16 x){ return __bfloat162float(x); }
// unpack 2 bf16 packed in a uint32
static __device__ __forceinline__ float2 upk2(unsigned int u){
  union { unsigned int i; float f; } a, b;
  a.i = u << 16;
  b.i = u & 0xffff0000u;
  float2 r; r.x = a.f; r.y = b.f; return r;
}
// pack two floats into a bf16x2 uint
static __device__ __forceinline__ unsigned int f2b2(float lo, float hi){
  bf16 l = __float2bfloat16(lo), h = __float2bfloat16(hi);
  unsigned short lb, hb;
  __builtin_memcpy(&lb, &l, 2); __builtin_memcpy(&hb, &h, 2);
  return (unsigned int)lb | ((unsigned int)hb << 16);
}
static __device__ __forceinline__ void sto(float* p, size_t i, float v){ p[i] = v; }
static __device__ __forceinline__ void sto(bf16* p, size_t i, float v){ p[i] = __float2bfloat16(v); }

// ---------------- workspace layout (bytes) ----------------
constexpr size_t MiB = 1ull << 20;
constexpr size_t OFF_C1   = 0;         // bf16 [1600,32,20,20] 40.96 MB
constexpr size_t OFF_C2   = 41*MiB;    // bf16 [1600,64,9,9]
constexpr size_t OFF_C3   = 58*MiB;    // bf16 [1600,3136]
constexpr size_t OFF_SE   = 69*MiB;    // f32  [1600,128]
constexpr size_t OFF_H    = 0;         // f32  [4800,128]
constexpr size_t OFF_XA   = 3*MiB;     // bf16 [4800,128]
constexpr size_t OFF_NORM = 6*MiB;     // bf16 [4800,128]
constexpr size_t OFF_QKV  = 9*MiB;     // bf16 [4800,384]
constexpr size_t OFF_Y    = 17*MiB;    // bf16 [4800,128]
constexpr size_t OFF_H1   = 20*MiB;    // f32  [4800,128]
constexpr size_t OFF_MLPH = 23*MiB;    // bf16 [4800,512]
constexpr size_t OFF_ADH  = 33*MiB;    // bf16 [4800,64]

// ================= conv1 via implicit-im2col MFMA =================
// x f32 [1600,4,84,84] -> relu -> bf16 [1600,32,20,20]
// GEMM per image: M=400, N=32, K=256 (c*64+ky*8+kx)
// Wave w owns m-tiles w*7+i, i unrolled compile-time (no dynamic acc indexing
// -> acc stays in VGPRs; round-5 scratch-spill fix).
__global__ __launch_bounds__(256) void conv1_kernel(
    const float* __restrict__ x, const float* __restrict__ w,
    const float* __restrict__ bias, bf16* __restrict__ out)
{
  __shared__ bf16 xs1[4*84*88];     // [c][row][88 pad]; reused as out-stage [32][408]
  int b = blockIdx.x;
  int t = threadIdx.x;
  const float4* xb4 = (const float4*)(x + (size_t)b*28224);
  for (int e = t; e < 7056; e += 256){
    int c = e / 1764, rem = e % 1764;
    int r = rem / 21, c4 = (rem % 21)*4;
    float4 f = xb4[e];
    *(uint2*)(xs1 + (c*84 + r)*88 + c4) = make_uint2(f2b2(f.x, f.y), f2b2(f.z, f.w));
  }
  __syncthreads();
  int lane = t & 63, wave = t >> 6;
  int quad = lane >> 4, r16 = lane & 15;
  f32x4 acc[7][2];
  #pragma unroll
  for (int i = 0; i < 7; ++i)
    #pragma unroll
    for (int j = 0; j < 2; ++j) acc[i][j] = (f32x4){0.f,0.f,0.f,0.f};
  for (int kc = 0; kc < 8; ++kc){
    int c = kc >> 1, ky = (kc & 1)*4 + quad;
    FragU bf_[2];
    #pragma unroll
    for (int tn = 0; tn < 2; ++tn){
      int oc = tn*16 + r16;
      const float* wp = w + oc*256 + kc*32 + quad*8;
      float4 wa = ((const float4*)wp)[0], wb = ((const float4*)wp)[1];
      bf_[tn].u[0] = f2b2(wa.x, wa.y); bf_[tn].u[1] = f2b2(wa.z, wa.w);
      bf_[tn].u[2] = f2b2(wb.x, wb.y); bf_[tn].u[3] = f2b2(wb.z, wb.w);
    }
    #pragma unroll
    for (int i = 0; i < 7; ++i){
      int tile = wave*7 + i;          // wave-uniform guard; wave 3 does 4 tiles
      if (tile < 25){
        int m = tile*16 + r16;
        int oy = m / 20, ox = m % 20;
        const bf16* p = xs1 + ((c*84 + 4*oy + ky)*88 + 4*ox);
        FragU a;
        a.d[0] = *(const uint2*)p;
        a.d[1] = *(const uint2*)(p + 4);
        acc[i][0] = __builtin_amdgcn_mfma_f32_16x16x32_bf16(a.s, bf_[0].s, acc[i][0], 0, 0, 0);
        acc[i][1] = __builtin_amdgcn_mfma_f32_16x16x32_bf16(a.s, bf_[1].s, acc[i][1], 0, 0, 0);
      }
    }
  }
  __syncthreads();   // staging reads done; reuse xs1 as out-stage [32][408]
  #pragma unroll
  for (int i = 0; i < 7; ++i){
    int tile = wave*7 + i;
    if (tile < 25){
      int m0 = tile*16 + quad*4;
      #pragma unroll
      for (int tn = 0; tn < 2; ++tn){
        int oc = tn*16 + r16;
        float bb = bias[oc];
        float v0 = fmaxf(acc[i][tn][0] + bb, 0.f);
        float v1 = fmaxf(acc[i][tn][1] + bb, 0.f);
        float v2 = fmaxf(acc[i][tn][2] + bb, 0.f);
        float v3 = fmaxf(acc[i][tn][3] + bb, 0.f);
        *(uint2*)(xs1 + oc*408 + m0) = make_uint2(f2b2(v0, v1), f2b2(v2, v3));
      }
    }
  }
  __syncthreads();
  bf16* outp = out + (size_t)b*12800;
  for (int e = t; e < 1600; e += 256){
    int oc = e / 50, col = e % 50;
    uint4 v = *(const uint4*)(xs1 + oc*408 + col*8);
    *(uint4*)(outp + oc*400 + col*8) = v;
  }
}

// ================= conv2 via implicit-im2col MFMA =================
// x bf16 [1600,32,20,20] -> relu -> bf16 [1600,64,9,9]
// GEMM per image: M=81 (pad 96), N=64, K=512 (c*16+ky*4+kx)
__global__ __launch_bounds__(256) void conv2_kernel(
    const bf16* __restrict__ x, const float* __restrict__ w,
    const float* __restrict__ bias, bf16* __restrict__ out)
{
  __shared__ bf16 xs2[32*20*24];    // [c][row][24 pad]; reused as out-stage [64][81]
  int b = blockIdx.x;
  int t = threadIdx.x;
  const unsigned int* xb = (const unsigned int*)(x + (size_t)b*12800);
  for (int p = t; p < 6400; p += 256){
    int c = p / 200, rem = p % 200;
    int r = rem / 10, cp = rem % 10;
    ((unsigned int*)xs2)[((c*20 + r)*24 + 2*cp) >> 1] = xb[p];
  }
  __syncthreads();
  int lane = t & 63, wave = t >> 6;
  int quad = lane >> 4, r16 = lane & 15;
  int oc = wave*16 + r16;     // wave owns one oc-tile
  f32x4 acc[6];
  #pragma unroll
  for (int i = 0; i < 6; ++i) acc[i] = (f32x4){0.f,0.f,0.f,0.f};
  for (int kc = 0; kc < 16; ++kc){
    const float* wp = w + oc*512 + kc*32 + quad*8;
    float4 wa = ((const float4*)wp)[0], wb = ((const float4*)wp)[1];
    FragU bfr;
    bfr.u[0] = f2b2(wa.x, wa.y); bfr.u[1] = f2b2(wa.z, wa.w);
    bfr.u[2] = f2b2(wb.x, wb.y); bfr.u[3] = f2b2(wb.z, wb.w);
    int c = kc*2 + (quad >> 1);
    int ky0 = (quad & 1)*2;
    #pragma unroll
    for (int tile = 0; tile < 6; ++tile){
      int m = tile*16 + r16; if (m > 80) m = 80;
      int oy = m / 9, ox = m % 9;
      int idx1 = (c*20 + 2*oy + ky0)*24 + 2*ox;
      const unsigned int* q1 = (const unsigned int*)(xs2 + idx1);
      const unsigned int* q2 = (const unsigned int*)(xs2 + idx1 + 24);
      FragU a;
      a.u[0] = q1[0]; a.u[1] = q1[1];
      a.u[2] = q2[0]; a.u[3] = q2[1];
      acc[tile] = __builtin_amdgcn_mfma_f32_16x16x32_bf16(a.s, bfr.s, acc[tile], 0, 0, 0);
    }
  }
  __syncthreads();   // staging reads done; reuse xs2 as out-stage [64][81]
  float bb = bias[oc];
  #pragma unroll
  for (int tile = 0; tile < 6; ++tile){
    #pragma unroll
    for (int r = 0; r < 4; ++r){
      int m = tile*16 + quad*4 + r;
      if (m < 81){
        float v = fmaxf(acc[tile][r] + bb, 0.f);
        xs2[oc*81 + m] = __float2bfloat16(v);
      }
    }
  }
  __syncthreads();
  const unsigned int* lsu = (const unsigned int*)xs2;
  unsigned int* op = (unsigned int*)(out + (size_t)b*5184);
  for (int e = t; e < 2592; e += 256) op[e] = lsu[e];
}

// ---------------- conv3 (VALU): bf16 [1600,64,9,9] -> relu -> bf16 [1600,3136] ----------------
__global__ __launch_bounds__(256) void conv3_kernel(
    const bf16* __restrict__ x, const float* __restrict__ w,
    const float* __restrict__ bias, bf16* __restrict__ out)
{
  __shared__ float xsf[5184];   // [64][81]
  int b = blockIdx.x;
  int t = threadIdx.x;
  const bf16* xb = x + (size_t)b*5184;
  for (int e = t; e < 2592; e += 256){
    unsigned int u = *(const unsigned int*)(xb + 2*e);
    float2 f = upk2(u);
    xsf[2*e] = f.x; xsf[2*e+1] = f.y;
  }
  __syncthreads();
  int oc = t & 63;
  int oy1 = t >> 6;             // 0..3
  bool two = (t < 192);         // second item: oy1+4
  float a1[7] = {}, a2[7] = {};
  const float* wb3 = w + oc*576;
  for (int c = 0; c < 64; ++c){
    #pragma unroll
    for (int ky = 0; ky < 3; ++ky){
      const float* wp = wb3 + c*9 + ky*3;
      float w0 = wp[0], w1 = wp[1], w2 = wp[2];
      const float* r1 = xsf + c*81 + (oy1+ky)*9;
      #pragma unroll
      for (int ox = 0; ox < 7; ++ox) a1[ox] += r1[ox]*w0 + r1[ox+1]*w1 + r1[ox+2]*w2;
      if (two){
        const float* r2 = xsf + c*81 + (oy1+4+ky)*9;
        #pragma unroll
        for (int ox = 0; ox < 7; ++ox) a2[ox] += r2[ox]*w0 + r2[ox+1]*w1 + r2[ox+2]*w2;
      }
    }
  }
  float bb = bias[oc];
  size_t o1 = (size_t)b*3136 + oc*49 + oy1*7;
  #pragma unroll
  for (int ox = 0; ox < 7; ++ox) out[o1+ox] = __float2bfloat16(fmaxf(a1[ox]+bb, 0.f));
  if (two){
    size_t o2 = (size_t)b*3136 + oc*49 + (oy1+4)*7;
    #pragma unroll
    for (int ox = 0; ox < 7; ++ox) out[o2+ox] = __float2bfloat16(fmaxf(a2[ox]+bb, 0.f));
  }
}

// ================= generic MFMA GEMM =================
// out = ACT(X @ W^T + bias) + add_scale*add;  X bf16 [M,K], W f32 [N,K]
// M%64==0, N%64==0, K%32==0. ACT: 0 none, 1 tanh, 2 gelu, 3 relu. OT: float or bf16.
template<int ACT, typename OT>
__global__ __launch_bounds__(256) void mgemm(
    const bf16* __restrict__ X, const float* __restrict__ W,
    const float* __restrict__ bias, const float* __restrict__ add, float add_scale,
    OT* __restrict__ out, int M, int N, int K)
{
  __shared__ bf16 Xs[64*40];
  __shared__ bf16 Ws[64*40];
  int nb = N >> 6;
  int bn = (blockIdx.x % nb) << 6;
  int bm = (blockIdx.x / nb) << 6;
  int t = threadIdx.x;
  int lane = t & 63, wave = t >> 6;
  int mw = wave >> 1, nw = wave & 1;
  int quad = lane >> 4, r16 = lane & 15;
  int srow = t >> 2, scol = (t & 3)*8;
  f32x4 acc[2][2];
  #pragma unroll
  for (int i = 0; i < 2; ++i)
    #pragma unroll
    for (int j = 0; j < 2; ++j) acc[i][j] = (f32x4){0.f,0.f,0.f,0.f};
  for (int k0 = 0; k0 < K; k0 += 32){
    uint4 xv = *(const uint4*)(X + (size_t)(bm + srow)*K + k0 + scol);
    uint2* xd = (uint2*)(Xs + srow*40 + scol);
    xd[0] = make_uint2(xv.x, xv.y); xd[1] = make_uint2(xv.z, xv.w);
    const float* wp = W + (size_t)(bn + srow)*K + k0 + scol;
    float4 wa = ((const float4*)wp)[0], wb = ((const float4*)wp)[1];
    uint2* wd = (uint2*)(Ws + srow*40 + scol);
    wd[0] = make_uint2(f2b2(wa.x, wa.y), f2b2(wa.z, wa.w));
    wd[1] = make_uint2(f2b2(wb.x, wb.y), f2b2(wb.z, wb.w));
    __syncthreads();
    FragU af[2], bf_[2];
    #pragma unroll
    for (int tm = 0; tm < 2; ++tm){
      const bf16* p = Xs + (mw*32 + tm*16 + r16)*40 + quad*8;
      af[tm].d[0] = *(const uint2*)p; af[tm].d[1] = *(const uint2*)(p + 4);
    }
    #pragma unroll
    for (int tn = 0; tn < 2; ++tn){
      const bf16* p = Ws + (nw*32 + tn*16 + r16)*40 + quad*8;
      bf_[tn].d[0] = *(const uint2*)p; bf_[tn].d[1] = *(const uint2*)(p + 4);
    }
    #pragma unroll
    for (int tm = 0; tm < 2; ++tm)
      #pragma unroll
      for (int tn = 0; tn < 2; ++tn)
        acc[tm][tn] = __builtin_amdgcn_mfma_f32_16x16x32_bf16(af[tm].s, bf_[tn].s, acc[tm][tn], 0, 0, 0);
    __syncthreads();
  }
  #pragma unroll
  for (int tm = 0; tm < 2; ++tm){
    #pragma unroll
    for (int tn = 0; tn < 2; ++tn){
      int n = bn + nw*32 + tn*16 + r16;
      float bb = bias[n];
      #pragma unroll
      for (int r = 0; r < 4; ++r){
        int m = bm + mw*32 + tm*16 + quad*4 + r;
        float v = acc[tm][tn][r] + bb;
        if (ACT == 1) v = tanhf(v);
        else if (ACT == 2) v = 0.5f*v*(1.0f + erff(v*0.70710678118f));
        else if (ACT == 3) v = fmaxf(v, 0.f);
        if (add) v += add_scale * add[(size_t)m*N + n];
        sto(out, (size_t)m*N + n, v);
      }
    }
  }
}

// ---------------- token build + pos embedding -> h f32 [4800,128] ----------------
__global__ __launch_bounds__(256) void token_kernel(
    const float* __restrict__ rtgs, const int* __restrict__ actions, const int* __restrict__ timesteps,
    const float* __restrict__ ret_w, const float* __restrict__ ret_b, const float* __restrict__ act_tab,
    const float* __restrict__ pos_emb, const float* __restrict__ gpe,
    const float* __restrict__ se, float* __restrict__ h)
{
  int idx = blockIdx.x*256 + threadIdx.x;   // 4800*128
  int c = idx & 127; int row = idx >> 7;
  int s = row % 150; int b = row / 150;
  int t = s / 3; int r = s - 3*t;
  float tok;
  if (r == 0)      tok = tanhf(rtgs[b*50+t] * ret_w[c] + ret_b[c]);
  else if (r == 1) tok = se[(b*50+t)*128 + c];
  else             tok = tanhf(act_tab[actions[b*50+t]*128 + c]);
  float pe = gpe[(size_t)timesteps[b]*128 + c] + pos_emb[s*128 + c];
  h[idx] = tok + pe;
}

// ---------------- LayerNorm over C=128 -> bf16 outputs ----------------
__global__ __launch_bounds__(256) void ln_kernel(
    const float* __restrict__ x,
    const float* __restrict__ g1, const float* __restrict__ be1, bf16* __restrict__ o1,
    const float* __restrict__ g2, const float* __restrict__ be2, bf16* o2)
{
  int lane = threadIdx.x & 63;
  int row = blockIdx.x*4 + (threadIdx.x >> 6);
  const float2 xv = *(const float2*)(x + (size_t)row*128 + lane*2);
  float s = xv.x + xv.y, sq = xv.x*xv.x + xv.y*xv.y;
  #pragma unroll
  for (int off = 32; off; off >>= 1){ s += __shfl_xor(s, off); sq += __shfl_xor(sq, off); }
  float mean = s * 0.0078125f;
  float var  = sq * 0.0078125f - mean*mean;
  float rstd = rsqrtf(var + 1e-5f);
  float n0 = (xv.x - mean)*rstd, n1 = (xv.y - mean)*rstd;
  int c0 = lane*2;
  ((unsigned int*)o1)[row*64 + lane] = f2b2(n0*g1[c0] + be1[c0], n1*g1[c0+1] + be1[c0+1]);
  if (o2)
    ((unsigned int*)o2)[row*64 + lane] = f2b2(n0*g2[c0] + be2[c0], n1*g2[c0+1] + be2[c0+1]);
}

// ---------------- attention: qkv bf16 [4800,384] (k|q|v), causal, online softmax ----------------
__global__ __launch_bounds__(256) void attn_kernel(const bf16* __restrict__ qkv, bf16* __restrict__ y)
{
  int bh = blockIdx.x;          // 32*8
  int hh = bh & 7; int b = bh >> 3;
  __shared__ float ks[150*16];
  __shared__ float vs[150*16];
  int t = threadIdx.x;
  for (int i = t; i < 2400; i += 256){
    int s = i >> 4; int d = i & 15;
    const bf16* base = qkv + (size_t)(b*150 + s)*384;
    ks[i] = b2f(base[hh*16 + d]);
    vs[i] = b2f(base[256 + hh*16 + d]);
  }
  __syncthreads();
  if (t < 150){
    const bf16* qr = qkv + (size_t)(b*150 + t)*384 + 128 + hh*16;
    float q[16];
    #pragma unroll
    for (int d = 0; d < 16; ++d) q[d] = b2f(qr[d]) * 0.25f;
    float m = -1e30f, l = 0.f, acc[16] = {};
    for (int j = 0; j <= t; ++j){
      const float* kr = ks + j*16;
      float s = 0.f;
      #pragma unroll
      for (int d = 0; d < 16; ++d) s += q[d]*kr[d];
      float mn = fmaxf(m, s);
      float corr = __expf(m - mn);
      float p = __expf(s - mn);
      l = l*corr + p;
      const float* vr = vs + j*16;
      #pragma unroll
      for (int d = 0; d < 16; ++d) acc[d] = acc[d]*corr + p*vr[d];
      m = mn;
    }
    float inv = 1.f / l;
    bf16* yr = y + (size_t)(b*150 + t)*128 + hh*16;
    #pragma unroll
    for (int d = 0; d < 16; ++d) yr[d] = __float2bfloat16(acc[d]*inv);
  }
}

// ---------------- fused final LN + head on state tokens -> f32 [1600,18] ----------------
__global__ __launch_bounds__(64) void head_kernel(
    const float* __restrict__ h, const float* __restrict__ g, const float* __restrict__ be,
    const float* __restrict__ hw, float* __restrict__ out)
{
  int bt = blockIdx.x;
  int lane = threadIdx.x;
  int b = bt / 50, t = bt % 50;
  const float* row = h + ((size_t)b*150 + 3*t + 1)*128;
  float2 xv = *(const float2*)(row + lane*2);
  float s = xv.x + xv.y, sq = xv.x*xv.x + xv.y*xv.y;
  #pragma unroll
  for (int off = 32; off; off >>= 1){ s += __shfl_xor(s, off); sq += __shfl_xor(sq, off); }
  float mean = s * 0.0078125f;
  float var  = sq * 0.0078125f - mean*mean;
  float rstd = rsqrtf(var + 1e-5f);
  int c0 = lane*2;
  __shared__ float sh[128];
  sh[c0]   = (xv.x-mean)*rstd*g[c0]   + be[c0];
  sh[c0+1] = (xv.y-mean)*rstd*g[c0+1] + be[c0+1];
  __syncthreads();
  if (lane < 18){
    const float* wr = hw + lane*128;
    float acc = 0.f;
    #pragma unroll
    for (int c = 0; c < 128; c += 4){
      float4 wf = *(const float4*)(wr + c);
      acc += sh[c]*wf.x + sh[c+1]*wf.y + sh[c+2]*wf.z + sh[c+3]*wf.w;
    }
    out[bt*18 + lane] = acc;
  }
}

// ---------------- launch ----------------
extern "C" void kernel_launch(void* const* d_in, const int* in_sizes, int n_in,
                              void* d_out, int out_size, void* d_ws, size_t ws_size,
                              hipStream_t stream)
{
  const float* states    = (const float*)d_in[0];
  const float* rtgs      = (const float*)d_in[1];
  const int*   actions   = (const int*)d_in[2];
  const int*   timesteps = (const int*)d_in[3];
  const float* pos_emb   = (const float*)d_in[5];
  const float* gpe       = (const float*)d_in[6];
  const float* c1_w = (const float*)d_in[7];  const float* c1_b = (const float*)d_in[8];
  const float* c2_w = (const float*)d_in[9];  const float* c2_b = (const float*)d_in[10];
  const float* c3_w = (const float*)d_in[11]; const float* c3_b = (const float*)d_in[12];
  const float* enc_w = (const float*)d_in[13]; const float* enc_b = (const float*)d_in[14];
  const float* ret_w = (const float*)d_in[15]; const float* ret_b = (const float*)d_in[16];
  const float* act_tab = (const float*)d_in[17];
  const float* ln_w = (const float*)d_in[18]; const float* ln_b = (const float*)d_in[19];
  const float* attn_w = (const float*)d_in[20]; const float* attn_b = (const float*)d_in[21];
  const float* mlp_w1 = (const float*)d_in[22]; const float* mlp_b1 = (const float*)d_in[23];
  const float* mlp_w2 = (const float*)d_in[24]; const float* mlp_b2 = (const float*)d_in[25];
  const float* ad_dw = (const float*)d_in[26]; const float* ad_db = (const float*)d_in[27];
  const float* ad_uw = (const float*)d_in[28]; const float* ad_ub = (const float*)d_in[29];
  const float* lnf_w = (const float*)d_in[30]; const float* lnf_b = (const float*)d_in[31];
  const float* head_w = (const float*)d_in[32];
  float* out = (float*)d_out;

  char* ws = (char*)d_ws;
  bf16* c1o  = (bf16*)(ws + OFF_C1);
  bf16* c2o  = (bf16*)(ws + OFF_C2);
  bf16* c3o  = (bf16*)(ws + OFF_C3);
  float* se  = (float*)(ws + OFF_SE);
  float* h   = (float*)(ws + OFF_H);
  bf16* xa   = (bf16*)(ws + OFF_XA);
  bf16* nrm  = (bf16*)(ws + OFF_NORM);
  bf16* qkv  = (bf16*)(ws + OFF_QKV);
  bf16* y    = (bf16*)(ws + OFF_Y);
  float* h1  = (float*)(ws + OFF_H1);
  bf16* mlph = (bf16*)(ws + OFF_MLPH);
  bf16* adh  = (bf16*)(ws + OFF_ADH);

  conv1_kernel<<<1600, 256, 0, stream>>>(states, c1_w, c1_b, c1o);
  conv2_kernel<<<1600, 256, 0, stream>>>(c1o, c2_w, c2_b, c2o);
  conv3_kernel<<<1600, 256, 0, stream>>>(c2o, c3_w, c3_b, c3o);
  // state_e = tanh(c3o @ enc_w^T + enc_b): M=1600, N=128, K=3136
  mgemm<1, float><<<25*2, 256, 0, stream>>>(c3o, enc_w, enc_b, nullptr, 0.f, se, 1600, 128, 3136);
  token_kernel<<<2400, 256, 0, stream>>>(rtgs, actions, timesteps, ret_w, ret_b, act_tab,
                                         pos_emb, gpe, se, h);

  for (int l = 0; l < 6; ++l){
    const float* g1 = ln_w + (l*3+0)*128; const float* be1 = ln_b + (l*3+0)*128;
    const float* g2 = ln_w + (l*3+1)*128; const float* be2 = ln_b + (l*3+1)*128;
    const float* g3 = ln_w + (l*3+2)*128; const float* be3 = ln_b + (l*3+2)*128;
    ln_kernel<<<1200, 256, 0, stream>>>(h, g1, be1, xa, g3, be3, nrm);
    mgemm<0, bf16><<<75*6, 256, 0, stream>>>(xa, attn_w + (size_t)l*4*16384, attn_b + l*4*128,
                                             nullptr, 0.f, qkv, 4800, 384, 128);
    attn_kernel<<<256, 256, 0, stream>>>(qkv, y);
    mgemm<0, float><<<75*2, 256, 0, stream>>>(y, attn_w + ((size_t)l*4+3)*16384, attn_b + (l*4+3)*128,
                                              h, 1.0f, h1, 4800, 128, 128);
    ln_kernel<<<1200, 256, 0, stream>>>(h1, g2, be2, xa, nullptr, nullptr, nullptr);
    mgemm<2, bf16><<<75*8, 256, 0, stream>>>(xa, mlp_w1 + (size_t)l*65536, mlp_b1 + l*512,
                                             nullptr, 0.f, mlph, 4800, 512, 128);
    mgemm<3, bf16><<<75*1, 256, 0, stream>>>(nrm, ad_dw + (size_t)l*8192, ad_db + l*64,
                                             nullptr, 0.f, adh, 4800, 64, 128);
    mgemm<0, float><<<75*2, 256, 0, stream>>>(mlph, mlp_w2 + (size_t)l*65536, mlp_b2 + l*128,
                                              h1, 2.0f, h, 4800, 128, 512);
    mgemm<0, float><<<75*2, 256, 0, stream>>>(adh, ad_uw + (size_t)l*8192, ad_ub + l*128,
                                              h, 1.0f, h, 4800, 128, 64);
  }
  head_kernel<<<1600, 64, 0, stream>>>(h, lnf_w, lnf_b, head_w, out);
}